// Round 1
// baseline (3427.507 us; speedup 1.0000x reference)
//
#include <hip/hip_runtime.h>
#include <math.h>

#define SS 512
#define BB 16
#define DD 768
#define HH 12
#define HDIM 64
#define EE 8
#define HID 3072
#define TT 8192   // SS*BB tokens
#define EPSV 1e-5f

// ---------------- LayerNorm: one block per token ----------------
__global__ __launch_bounds__(256) void ln_kernel(const float* __restrict__ x,
    const float* __restrict__ w, const float* __restrict__ b, float* __restrict__ out) {
  int t = blockIdx.x, tid = threadIdx.x;
  const float* row = x + (size_t)t * DD;
  float s = 0.f, ss = 0.f;
  for (int i = tid; i < DD; i += 256) { float v = row[i]; s += v; ss += v * v; }
  for (int o = 32; o > 0; o >>= 1) { s += __shfl_down(s, o); ss += __shfl_down(ss, o); }
  __shared__ float sw[4], ssw[4];
  int wid = tid >> 6, lane = tid & 63;
  if (lane == 0) { sw[wid] = s; ssw[wid] = ss; }
  __syncthreads();
  if (tid == 0) {
    float s1 = sw[0] + sw[1] + sw[2] + sw[3];
    float s2 = ssw[0] + ssw[1] + ssw[2] + ssw[3];
    float mean = s1 / DD;
    float var = s2 / DD - mean * mean;
    sw[0] = mean; ssw[0] = rsqrtf(var + EPSV);
  }
  __syncthreads();
  float mean = sw[0], inv = ssw[0];
  float* orow = out + (size_t)t * DD;
  for (int i = tid; i < DD; i += 256) orow[i] = (row[i] - mean) * inv * w[i] + b[i];
}

// ---------------- generic fp32 tiled GEMM: C = A@W + bias (+res) ----------------
// MODE 0: C = A@W + bias      MODE 1: C = res + A@W + bias
template<int MODE>
__global__ __launch_bounds__(256) void gemm64(const float* __restrict__ A,
    const float* __restrict__ W, const float* __restrict__ bias,
    const float* __restrict__ res, float* __restrict__ C, int M, int N, int K) {
  __shared__ float As[16][65];
  __shared__ float Ws[16][65];
  const int bm = blockIdx.x * 64, bn = blockIdx.y * 64;
  const int tid = threadIdx.x, tx = tid & 15, ty = tid >> 4;
  float acc[4][4] = {};
  for (int k0 = 0; k0 < K; k0 += 16) {
#pragma unroll
    for (int l = 0; l < 4; ++l) {
      int i = tid + l * 256; int m = i >> 4, kk = i & 15;
      As[kk][m] = A[(size_t)(bm + m) * K + k0 + kk];
    }
#pragma unroll
    for (int l = 0; l < 4; ++l) {
      int i = tid + l * 256; int kk = i >> 6, n = i & 63;
      Ws[kk][n] = W[(size_t)(k0 + kk) * N + bn + n];
    }
    __syncthreads();
#pragma unroll
    for (int kk = 0; kk < 16; ++kk) {
      float a[4], b[4];
#pragma unroll
      for (int i = 0; i < 4; ++i) a[i] = As[kk][ty * 4 + i];
#pragma unroll
      for (int j = 0; j < 4; ++j) b[j] = Ws[kk][tx * 4 + j];
#pragma unroll
      for (int i = 0; i < 4; ++i)
#pragma unroll
        for (int j = 0; j < 4; ++j) acc[i][j] += a[i] * b[j];
    }
    __syncthreads();
  }
#pragma unroll
  for (int i = 0; i < 4; ++i) {
    int r = bm + ty * 4 + i;
#pragma unroll
    for (int j = 0; j < 4; ++j) {
      int c = bn + tx * 4 + j;
      float val = acc[i][j] + bias[c];
      if (MODE == 1) val += res[(size_t)r * N + c];
      C[(size_t)r * N + c] = val;
    }
  }
}

// ---------------- flash-style attention ----------------
// grid: (SS/64, BB, HH); q is pre-LN'd projection, layout [t=s*BB+b][h*64+d]
__global__ __launch_bounds__(256) void attn_kernel(const float* __restrict__ q,
    const float* __restrict__ k, const float* __restrict__ v, float* __restrict__ o) {
  const int qt = blockIdx.x, bidx = blockIdx.y, hidx = blockIdx.z;
  const int tid = threadIdx.x, tx = tid & 15, ty = tid >> 4;
  const int s0 = qt * 64;
  __shared__ float Qt[64][65];
  __shared__ float KV[64][65];
  __shared__ float P[64][65];
  __shared__ float mrow[64], lrow[64], arow[64];
  for (int i = tid; i < 64 * 64; i += 256) {
    int r = i >> 6, d = i & 63;
    Qt[r][d] = q[((size_t)(s0 + r) * BB + bidx) * DD + hidx * HDIM + d] * 0.125f;
  }
  if (tid < 64) { mrow[tid] = -1e30f; lrow[tid] = 0.f; }
  float oacc[4][4] = {};
  __syncthreads();
  for (int t0 = 0; t0 < SS; t0 += 64) {
    for (int i = tid; i < 64 * 64; i += 256) {
      int r = i >> 6, d = i & 63;
      KV[r][d] = k[((size_t)(t0 + r) * BB + bidx) * DD + hidx * HDIM + d];
    }
    __syncthreads();
    float sacc[4][4] = {};
#pragma unroll
    for (int d = 0; d < 64; ++d) {
      float a[4], bbv[4];
#pragma unroll
      for (int i = 0; i < 4; ++i) a[i] = Qt[ty * 4 + i][d];
#pragma unroll
      for (int j = 0; j < 4; ++j) bbv[j] = KV[tx * 4 + j][d];
#pragma unroll
      for (int i = 0; i < 4; ++i)
#pragma unroll
        for (int j = 0; j < 4; ++j) sacc[i][j] += a[i] * bbv[j];
    }
#pragma unroll
    for (int i = 0; i < 4; ++i)
#pragma unroll
      for (int j = 0; j < 4; ++j) P[ty * 4 + i][tx * 4 + j] = sacc[i][j];
    __syncthreads();
    // per-row online softmax (threads 0..63); others help load V below
    if (tid < 64) {
      int r = tid;
      float mold = mrow[r], tm = mold;
      for (int j = 0; j < 64; ++j) tm = fmaxf(tm, P[r][j]);
      float alpha = __expf(mold - tm);
      float sum = 0.f;
      for (int j = 0; j < 64; ++j) { float p = __expf(P[r][j] - tm); P[r][j] = p; sum += p; }
      lrow[r] = lrow[r] * alpha + sum;
      mrow[r] = tm; arow[r] = alpha;
    }
    for (int i = tid; i < 64 * 64; i += 256) {
      int r = i >> 6, d = i & 63;
      KV[r][d] = v[((size_t)(t0 + r) * BB + bidx) * DD + hidx * HDIM + d];
    }
    __syncthreads();
    float al[4];
#pragma unroll
    for (int i = 0; i < 4; ++i) al[i] = arow[ty * 4 + i];
#pragma unroll
    for (int i = 0; i < 4; ++i)
#pragma unroll
      for (int j = 0; j < 4; ++j) oacc[i][j] *= al[i];
#pragma unroll
    for (int jj = 0; jj < 64; ++jj) {
      float p[4], vv[4];
#pragma unroll
      for (int i = 0; i < 4; ++i) p[i] = P[ty * 4 + i][jj];
#pragma unroll
      for (int j = 0; j < 4; ++j) vv[j] = KV[jj][tx * 4 + j];
#pragma unroll
      for (int i = 0; i < 4; ++i)
#pragma unroll
        for (int j = 0; j < 4; ++j) oacc[i][j] += p[i] * vv[j];
    }
    __syncthreads();
  }
#pragma unroll
  for (int i = 0; i < 4; ++i) {
    int r = ty * 4 + i;
    float invl = 1.f / lrow[r];
#pragma unroll
    for (int j = 0; j < 4; ++j) {
      int c = tx * 4 + j;
      o[((size_t)(s0 + r) * BB + bidx) * DD + hidx * HDIM + c] = oacc[i][j] * invl;
    }
  }
}

// ---------------- MoE routing: one wave per token ----------------
__global__ __launch_bounds__(256) void route_kernel(const float* __restrict__ tln,
    const float* __restrict__ wg, const float* __restrict__ bg,
    int* __restrict__ idx, float* __restrict__ gate, int* __restrict__ cnt) {
  int token = blockIdx.x * 4 + (threadIdx.x >> 6);
  int lane = threadIdx.x & 63;
  const float* row = tln + (size_t)token * DD;
  float acc[EE];
#pragma unroll
  for (int e = 0; e < EE; ++e) acc[e] = 0.f;
  for (int d = lane; d < DD; d += 64) {
    float tv = row[d];
#pragma unroll
    for (int e = 0; e < EE; ++e) acc[e] += tv * wg[d * EE + e];
  }
  for (int o = 32; o > 0; o >>= 1)
#pragma unroll
    for (int e = 0; e < EE; ++e) acc[e] += __shfl_down(acc[e], o);
  if (lane == 0) {
#pragma unroll
    for (int e = 0; e < EE; ++e) acc[e] += bg[e];
    int best = 0; float bm = acc[0];
#pragma unroll
    for (int e = 1; e < EE; ++e) if (acc[e] > bm) { bm = acc[e]; best = e; }
    float sum = 0.f;
#pragma unroll
    for (int e = 0; e < EE; ++e) sum += __expf(acc[e] - bm);
    idx[token] = best;
    gate[token] = 1.0f / sum;
    atomicAdd(&cnt[best], 1);
  }
}

__global__ void prefix_kernel(const int* __restrict__ cnt, int* __restrict__ off,
                              int* __restrict__ tb, int* __restrict__ cur) {
  if (threadIdx.x == 0 && blockIdx.x == 0) {
    int o = 0, t = 0;
    for (int e = 0; e < EE; ++e) {
      off[e] = o; tb[e] = t;
      o += cnt[e]; t += (cnt[e] + 63) >> 6;
      cur[e] = 0;
    }
    off[EE] = o; tb[EE] = t;
  }
}

__global__ __launch_bounds__(256) void scatter_kernel(const int* __restrict__ idx,
    const int* __restrict__ off, int* __restrict__ cur, int* __restrict__ perm) {
  int t = blockIdx.x * 256 + threadIdx.x;
  if (t < TT) {
    int e = idx[t];
    int p = atomicAdd(&cur[e], 1);
    perm[off[e] + p] = t;
  }
}

// ---------------- expert GEMM 1: h = gelu(t @ w1[e] + b1[e]) (gathered rows) ----------------
__global__ __launch_bounds__(256) void egemm1(const float* __restrict__ Aall,
    const float* __restrict__ w1, const float* __restrict__ b1,
    const int* __restrict__ perm, const int* __restrict__ off,
    const int* __restrict__ tb, const int* __restrict__ cnt,
    float* __restrict__ hbuf) {
  const int bx = blockIdx.x;
  if (bx >= tb[EE]) return;
  int e = 0;
  while (e < EE - 1 && tb[e + 1] <= bx) ++e;
  const int lt = bx - tb[e];
  const int cnte = cnt[e];
  const int slot0 = off[e] + lt * 64;
  const int bn = blockIdx.y * 64;
  const int tid = threadIdx.x, tx = tid & 15, ty = tid >> 4;
  __shared__ int stok[64];
  __shared__ float As[16][65];
  __shared__ float Ws[16][65];
  if (tid < 64) stok[tid] = (lt * 64 + tid < cnte) ? perm[slot0 + tid] : -1;
  __syncthreads();
  float acc[4][4] = {};
  const float* Wexp = w1 + (size_t)e * DD * HID;
  for (int k0 = 0; k0 < DD; k0 += 16) {
#pragma unroll
    for (int l = 0; l < 4; ++l) {
      int i = tid + l * 256; int m = i >> 4, kk = i & 15;
      int tok = stok[m];
      As[kk][m] = (tok >= 0) ? Aall[(size_t)tok * DD + k0 + kk] : 0.f;
    }
#pragma unroll
    for (int l = 0; l < 4; ++l) {
      int i = tid + l * 256; int kk = i >> 6, n = i & 63;
      Ws[kk][n] = Wexp[(size_t)(k0 + kk) * HID + bn + n];
    }
    __syncthreads();
#pragma unroll
    for (int kk = 0; kk < 16; ++kk) {
      float a[4], b[4];
#pragma unroll
      for (int i = 0; i < 4; ++i) a[i] = As[kk][ty * 4 + i];
#pragma unroll
      for (int j = 0; j < 4; ++j) b[j] = Ws[kk][tx * 4 + j];
#pragma unroll
      for (int i = 0; i < 4; ++i)
#pragma unroll
        for (int j = 0; j < 4; ++j) acc[i][j] += a[i] * b[j];
    }
    __syncthreads();
  }
#pragma unroll
  for (int i = 0; i < 4; ++i) {
    int m = ty * 4 + i;
    if (lt * 64 + m >= cnte) continue;
#pragma unroll
    for (int j = 0; j < 4; ++j) {
      int c = bn + tx * 4 + j;
      float xv = acc[i][j] + b1[e * HID + c];
      float g = 0.5f * xv * (1.f + erff(xv * 0.70710678118654752f));
      hbuf[(size_t)(slot0 + m) * HID + c] = g;
    }
  }
}

// ---------------- expert GEMM 2: out[tok] = x1[tok] + gate*(h @ w2[e] + b2[e]) ----------------
__global__ __launch_bounds__(256) void egemm2(const float* __restrict__ hbuf,
    const float* __restrict__ w2, const float* __restrict__ b2,
    const int* __restrict__ perm, const int* __restrict__ off,
    const int* __restrict__ tb, const int* __restrict__ cnt,
    const float* __restrict__ gate, const float* __restrict__ x1,
    float* __restrict__ out) {
  const int bx = blockIdx.x;
  if (bx >= tb[EE]) return;
  int e = 0;
  while (e < EE - 1 && tb[e + 1] <= bx) ++e;
  const int lt = bx - tb[e];
  const int cnte = cnt[e];
  const int slot0 = off[e] + lt * 64;
  const int bn = blockIdx.y * 64;
  const int tid = threadIdx.x, tx = tid & 15, ty = tid >> 4;
  __shared__ int stok[64];
  __shared__ float As[16][65];
  __shared__ float Ws[16][65];
  if (tid < 64) stok[tid] = (lt * 64 + tid < cnte) ? perm[slot0 + tid] : -1;
  __syncthreads();
  float acc[4][4] = {};
  const float* Wexp = w2 + (size_t)e * HID * DD;
  for (int k0 = 0; k0 < HID; k0 += 16) {
#pragma unroll
    for (int l = 0; l < 4; ++l) {
      int i = tid + l * 256; int m = i >> 4, kk = i & 15;
      bool valid = (lt * 64 + m < cnte);
      As[kk][m] = valid ? hbuf[(size_t)(slot0 + m) * HID + k0 + kk] : 0.f;
    }
#pragma unroll
    for (int l = 0; l < 4; ++l) {
      int i = tid + l * 256; int kk = i >> 6, n = i & 63;
      Ws[kk][n] = Wexp[(size_t)(k0 + kk) * DD + bn + n];
    }
    __syncthreads();
#pragma unroll
    for (int kk = 0; kk < 16; ++kk) {
      float a[4], b[4];
#pragma unroll
      for (int i = 0; i < 4; ++i) a[i] = As[kk][ty * 4 + i];
#pragma unroll
      for (int j = 0; j < 4; ++j) b[j] = Ws[kk][tx * 4 + j];
#pragma unroll
      for (int i = 0; i < 4; ++i)
#pragma unroll
        for (int j = 0; j < 4; ++j) acc[i][j] += a[i] * b[j];
    }
    __syncthreads();
  }
#pragma unroll
  for (int i = 0; i < 4; ++i) {
    int m = ty * 4 + i;
    if (lt * 64 + m >= cnte) continue;
    int tok = stok[m];
    float g = gate[tok];
#pragma unroll
    for (int j = 0; j < 4; ++j) {
      int c = bn + tx * 4 + j;
      float val = acc[i][j] + b2[e * DD + c];
      out[(size_t)tok * DD + c] = x1[(size_t)tok * DD + c] + g * val;
    }
  }
}

extern "C" void kernel_launch(void* const* d_in, const int* in_sizes, int n_in,
                              void* d_out, int out_size, void* d_ws, size_t ws_size,
                              hipStream_t stream) {
  const float* x     = (const float*)d_in[0];
  const float* ln1_w = (const float*)d_in[1];
  const float* ln1_b = (const float*)d_in[2];
  const float* wq    = (const float*)d_in[3];
  const float* bq    = (const float*)d_in[4];
  const float* wk    = (const float*)d_in[5];
  const float* bk    = (const float*)d_in[6];
  const float* wv    = (const float*)d_in[7];
  const float* bv    = (const float*)d_in[8];
  const float* wo    = (const float*)d_in[9];
  const float* bo    = (const float*)d_in[10];
  const float* ln2_w = (const float*)d_in[11];
  const float* ln2_b = (const float*)d_in[12];
  const float* wg    = (const float*)d_in[13];
  const float* bg    = (const float*)d_in[14];
  const float* w1    = (const float*)d_in[15];
  const float* b1    = (const float*)d_in[16];
  const float* w2    = (const float*)d_in[17];
  const float* b2    = (const float*)d_in[18];
  float* out = (float*)d_out;
  float* ws = (float*)d_ws;

  const size_t TD = (size_t)TT * DD;
  float* A0 = ws;              // q_in, then attn output
  float* A1 = ws + TD;         // q, then x1
  float* A2 = ws + 2 * TD;     // k, then t_ln
  float* A3 = ws + 3 * TD;     // v
  float* hbuf = ws + 4 * TD;   // [TT, HID] permuted expert activations
  int* meta = (int*)(ws + 4 * TD + (size_t)TT * HID);
  int* idx   = meta;
  float* gate = (float*)(meta + TT);
  int* perm  = meta + 2 * TT;
  int* cnt   = meta + 3 * TT;  // 8
  int* off   = cnt + 8;        // 9
  int* tb    = off + 9;        // 9
  int* cur   = tb + 9;         // 8

  hipMemsetAsync(cnt, 0, 8 * sizeof(int), stream);

  ln_kernel<<<TT, 256, 0, stream>>>(x, ln1_w, ln1_b, A0);

  dim3 g(TT / 64, DD / 64);
  gemm64<0><<<g, 256, 0, stream>>>(A0, wq, bq, nullptr, A1, TT, DD, DD);
  gemm64<0><<<g, 256, 0, stream>>>(x,  wk, bk, nullptr, A2, TT, DD, DD);
  gemm64<0><<<g, 256, 0, stream>>>(x,  wv, bv, nullptr, A3, TT, DD, DD);

  attn_kernel<<<dim3(SS / 64, BB, HH), 256, 0, stream>>>(A1, A2, A3, A0);

  gemm64<1><<<g, 256, 0, stream>>>(A0, wo, bo, x, A1, TT, DD, DD);  // x1

  ln_kernel<<<TT, 256, 0, stream>>>(A1, ln2_w, ln2_b, A2);          // t_ln

  route_kernel<<<TT / 4, 256, 0, stream>>>(A2, wg, bg, idx, gate, cnt);
  prefix_kernel<<<1, 64, 0, stream>>>(cnt, off, tb, cur);
  scatter_kernel<<<TT / 256, 256, 0, stream>>>(idx, off, cur, perm);

  egemm1<<<dim3(136, HID / 64), 256, 0, stream>>>(A2, w1, b1, perm, off, tb, cnt, hbuf);
  egemm2<<<dim3(136, DD / 64), 256, 0, stream>>>(hbuf, w2, b2, perm, off, tb, cnt, gate, A1, out);
}

// Round 2
// 1187.833 us; speedup vs baseline: 2.8855x; 2.8855x over previous
//
#include <hip/hip_runtime.h>
#include <math.h>

#define SS 512
#define BB 16
#define DD 768
#define HH 12
#define HDIM 64
#define EE 8
#define HID 3072
#define TT 8192   // SS*BB tokens
#define EPSV 1e-5f
#define KVSTR 1536
#define LDSP 40   // padded LDS row stride in shorts (80 B)

typedef __attribute__((ext_vector_type(8))) short s16x8;
typedef __attribute__((ext_vector_type(4))) short s16x4;
typedef __attribute__((ext_vector_type(4))) float f32x4;

__device__ inline short f2bf(float f) {
  unsigned u = __builtin_bit_cast(unsigned, f);
  unsigned r = (u + 0x7fffu + ((u >> 16) & 1u)) >> 16;
  return (short)r;
}

// ---------------- transpose + convert: W[K,N] fp32 -> Wt[N,K] bf16 ----------------
__global__ __launch_bounds__(256) void transpose_bf16(const float* __restrict__ W,
    short* __restrict__ Wt, int K, int N) {
  const float* Wz = W + (size_t)blockIdx.z * K * N;
  short* Wtz = Wt + (size_t)blockIdx.z * K * N;
  int k0 = blockIdx.x * 64, n0 = blockIdx.y * 64;
  __shared__ float t[64][65];
  for (int i = threadIdx.x; i < 4096; i += 256) {
    int r = i >> 6, c = i & 63;
    t[r][c] = Wz[(size_t)(k0 + r) * N + n0 + c];
  }
  __syncthreads();
  for (int i = threadIdx.x; i < 4096; i += 256) {
    int r = i >> 6, c = i & 63;
    Wtz[(size_t)(n0 + r) * K + k0 + c] = f2bf(t[c][r]);
  }
}

// ---------------- LayerNorm: one block per token ----------------
__global__ __launch_bounds__(256) void ln_kernel(const float* __restrict__ x,
    const float* __restrict__ w, const float* __restrict__ b, float* __restrict__ out) {
  int t = blockIdx.x, tid = threadIdx.x;
  const float* row = x + (size_t)t * DD;
  float s = 0.f, ss = 0.f;
  for (int i = tid; i < DD; i += 256) { float v = row[i]; s += v; ss += v * v; }
  for (int o = 32; o > 0; o >>= 1) { s += __shfl_down(s, o); ss += __shfl_down(ss, o); }
  __shared__ float sw[4], ssw[4];
  int wid = tid >> 6, lane = tid & 63;
  if (lane == 0) { sw[wid] = s; ssw[wid] = ss; }
  __syncthreads();
  if (tid == 0) {
    float s1 = sw[0] + sw[1] + sw[2] + sw[3];
    float s2 = ssw[0] + ssw[1] + ssw[2] + ssw[3];
    float mean = s1 / DD;
    float var = s2 / DD - mean * mean;
    sw[0] = mean; ssw[0] = rsqrtf(var + EPSV);
  }
  __syncthreads();
  float mean = sw[0], inv = ssw[0];
  float* orow = out + (size_t)t * DD;
  for (int i = tid; i < DD; i += 256) orow[i] = (row[i] - mean) * inv * w[i] + b[i];
}

// ---------------- bf16 MFMA GEMM: C = A@W^T(+bias)(+res) ----------------
// A fp32 [M,K]; Wt bf16 [N,K]; 128x128 tile, BK=32, 4 waves of 64x64.
// MODE 0: bias. MODE 1: bias + res. MODE 2: dual bias split at DD (KV fused).
template<int MODE>
__global__ __launch_bounds__(256) void mgemm(const float* __restrict__ A,
    const short* __restrict__ Wt, const float* __restrict__ bias,
    const float* __restrict__ bias2, const float* __restrict__ res,
    float* __restrict__ C, int M, int N, int K) {
  __shared__ short As[128 * LDSP];
  __shared__ short Bs[128 * LDSP];
  const int tid = threadIdx.x;
  const int wave = tid >> 6, lane = tid & 63;
  const int wr = (wave >> 1) * 64, wc = (wave & 1) * 64;
  const int l16 = lane & 15, quad = lane >> 4;
  const int bm = blockIdx.x * 128, bn = blockIdx.y * 128;
  f32x4 acc[4][4] = {};
  for (int k0 = 0; k0 < K; k0 += 32) {
#pragma unroll
    for (int l = 0; l < 4; ++l) {
      int c = tid + l * 256, m = c >> 3, kq = c & 7;
      const float4 v = *(const float4*)(A + (size_t)(bm + m) * K + k0 + kq * 4);
      s16x4 s; s.x = f2bf(v.x); s.y = f2bf(v.y); s.z = f2bf(v.z); s.w = f2bf(v.w);
      *(s16x4*)(&As[m * LDSP + kq * 4]) = s;
    }
#pragma unroll
    for (int l = 0; l < 2; ++l) {
      int c = tid + l * 256, n = c >> 2, kq = c & 3;
      *(s16x8*)(&Bs[n * LDSP + kq * 8]) = *(const s16x8*)(Wt + (size_t)(bn + n) * K + k0 + kq * 8);
    }
    __syncthreads();
    s16x8 af[4], bfr[4];
#pragma unroll
    for (int i = 0; i < 4; ++i) af[i] = *(s16x8*)(&As[(wr + i * 16 + l16) * LDSP + quad * 8]);
#pragma unroll
    for (int j = 0; j < 4; ++j) bfr[j] = *(s16x8*)(&Bs[(wc + j * 16 + l16) * LDSP + quad * 8]);
#pragma unroll
    for (int i = 0; i < 4; ++i)
#pragma unroll
      for (int j = 0; j < 4; ++j)
        acc[i][j] = __builtin_amdgcn_mfma_f32_16x16x32_bf16(af[i], bfr[j], acc[i][j], 0, 0, 0);
    __syncthreads();
  }
#pragma unroll
  for (int i = 0; i < 4; ++i) {
#pragma unroll
    for (int r = 0; r < 4; ++r) {
      int row = bm + wr + i * 16 + quad * 4 + r;
#pragma unroll
      for (int j = 0; j < 4; ++j) {
        int col = bn + wc + j * 16 + l16;
        float bv = (MODE == 2) ? (col >= DD ? bias2[col - DD] : bias[col]) : bias[col];
        float val = acc[i][j][r] + bv;
        if (MODE == 1) val += res[(size_t)row * N + col];
        C[(size_t)row * N + col] = val;
      }
    }
  }
}

// ---------------- flash-style attention (fp32) ----------------
// q [T, DD]; k,v from fused kv buffer [T, KVSTR] (v base pre-offset by DD)
__global__ __launch_bounds__(256) void attn_kernel(const float* __restrict__ q,
    const float* __restrict__ k, const float* __restrict__ v, float* __restrict__ o) {
  const int qt = blockIdx.x, bidx = blockIdx.y, hidx = blockIdx.z;
  const int tid = threadIdx.x, tx = tid & 15, ty = tid >> 4;
  const int s0 = qt * 64;
  __shared__ float Qt[64][65];
  __shared__ float KV[64][65];
  __shared__ float P[64][65];
  __shared__ float mrow[64], lrow[64], arow[64];
  for (int i = tid; i < 64 * 64; i += 256) {
    int r = i >> 6, d = i & 63;
    Qt[r][d] = q[((size_t)(s0 + r) * BB + bidx) * DD + hidx * HDIM + d] * 0.125f;
  }
  if (tid < 64) { mrow[tid] = -1e30f; lrow[tid] = 0.f; }
  float oacc[4][4] = {};
  __syncthreads();
  for (int t0 = 0; t0 < SS; t0 += 64) {
    for (int i = tid; i < 64 * 64; i += 256) {
      int r = i >> 6, d = i & 63;
      KV[r][d] = k[((size_t)(t0 + r) * BB + bidx) * KVSTR + hidx * HDIM + d];
    }
    __syncthreads();
    float sacc[4][4] = {};
#pragma unroll
    for (int d = 0; d < 64; ++d) {
      float a[4], bbv[4];
#pragma unroll
      for (int i = 0; i < 4; ++i) a[i] = Qt[ty * 4 + i][d];
#pragma unroll
      for (int j = 0; j < 4; ++j) bbv[j] = KV[tx * 4 + j][d];
#pragma unroll
      for (int i = 0; i < 4; ++i)
#pragma unroll
        for (int j = 0; j < 4; ++j) sacc[i][j] += a[i] * bbv[j];
    }
#pragma unroll
    for (int i = 0; i < 4; ++i)
#pragma unroll
      for (int j = 0; j < 4; ++j) P[ty * 4 + i][tx * 4 + j] = sacc[i][j];
    __syncthreads();
    if (tid < 64) {
      int r = tid;
      float mold = mrow[r], tm = mold;
      for (int j = 0; j < 64; ++j) tm = fmaxf(tm, P[r][j]);
      float alpha = __expf(mold - tm);
      float sum = 0.f;
      for (int j = 0; j < 64; ++j) { float p = __expf(P[r][j] - tm); P[r][j] = p; sum += p; }
      lrow[r] = lrow[r] * alpha + sum;
      mrow[r] = tm; arow[r] = alpha;
    }
    for (int i = tid; i < 64 * 64; i += 256) {
      int r = i >> 6, d = i & 63;
      KV[r][d] = v[((size_t)(t0 + r) * BB + bidx) * KVSTR + hidx * HDIM + d];
    }
    __syncthreads();
    float al[4];
#pragma unroll
    for (int i = 0; i < 4; ++i) al[i] = arow[ty * 4 + i];
#pragma unroll
    for (int i = 0; i < 4; ++i)
#pragma unroll
      for (int j = 0; j < 4; ++j) oacc[i][j] *= al[i];
#pragma unroll
    for (int jj = 0; jj < 64; ++jj) {
      float p[4], vv[4];
#pragma unroll
      for (int i = 0; i < 4; ++i) p[i] = P[ty * 4 + i][jj];
#pragma unroll
      for (int j = 0; j < 4; ++j) vv[j] = KV[jj][tx * 4 + j];
#pragma unroll
      for (int i = 0; i < 4; ++i)
#pragma unroll
        for (int j = 0; j < 4; ++j) oacc[i][j] += p[i] * vv[j];
    }
    __syncthreads();
  }
#pragma unroll
  for (int i = 0; i < 4; ++i) {
    int r = ty * 4 + i;
    float invl = 1.f / lrow[r];
#pragma unroll
    for (int j = 0; j < 4; ++j) {
      int c = tx * 4 + j;
      o[((size_t)(s0 + r) * BB + bidx) * DD + hidx * HDIM + c] = oacc[i][j] * invl;
    }
  }
}

// ---------------- MoE routing ----------------
__global__ __launch_bounds__(256) void route_kernel(const float* __restrict__ tln,
    const float* __restrict__ wg, const float* __restrict__ bg,
    int* __restrict__ idx, float* __restrict__ gate, int* __restrict__ cnt) {
  int token = blockIdx.x * 4 + (threadIdx.x >> 6);
  int lane = threadIdx.x & 63;
  const float* row = tln + (size_t)token * DD;
  float acc[EE];
#pragma unroll
  for (int e = 0; e < EE; ++e) acc[e] = 0.f;
  for (int d = lane; d < DD; d += 64) {
    float tv = row[d];
#pragma unroll
    for (int e = 0; e < EE; ++e) acc[e] += tv * wg[d * EE + e];
  }
  for (int o = 32; o > 0; o >>= 1)
#pragma unroll
    for (int e = 0; e < EE; ++e) acc[e] += __shfl_down(acc[e], o);
  if (lane == 0) {
#pragma unroll
    for (int e = 0; e < EE; ++e) acc[e] += bg[e];
    int best = 0; float bm = acc[0];
#pragma unroll
    for (int e = 1; e < EE; ++e) if (acc[e] > bm) { bm = acc[e]; best = e; }
    float sum = 0.f;
#pragma unroll
    for (int e = 0; e < EE; ++e) sum += __expf(acc[e] - bm);
    idx[token] = best;
    gate[token] = 1.0f / sum;
    atomicAdd(&cnt[best], 1);
  }
}

__global__ void prefix_kernel(const int* __restrict__ cnt, int* __restrict__ off,
                              int* __restrict__ tb, int* __restrict__ cur) {
  if (threadIdx.x == 0 && blockIdx.x == 0) {
    int o = 0, t = 0;
    for (int e = 0; e < EE; ++e) {
      off[e] = o; tb[e] = t;
      o += cnt[e]; t += (cnt[e] + 127) >> 7;
      cur[e] = 0;
    }
    off[EE] = o; tb[EE] = t;
  }
}

__global__ __launch_bounds__(256) void scatter_kernel(const int* __restrict__ idx,
    const int* __restrict__ off, int* __restrict__ cur, int* __restrict__ perm) {
  int t = blockIdx.x * 256 + threadIdx.x;
  if (t < TT) {
    int e = idx[t];
    int p = atomicAdd(&cur[e], 1);
    perm[off[e] + p] = t;
  }
}

// ---------------- expert GEMM 1 (MFMA): h = gelu(t @ w1[e]) -> bf16 ----------------
__global__ __launch_bounds__(256) void egemm1(const float* __restrict__ Aall,
    const short* __restrict__ w1t, const float* __restrict__ b1,
    const int* __restrict__ perm, const int* __restrict__ off,
    const int* __restrict__ tb, const int* __restrict__ cnt,
    short* __restrict__ hbuf) {
  const int bx = blockIdx.x;
  if (bx >= tb[EE]) return;
  int e = 0;
  while (e < EE - 1 && tb[e + 1] <= bx) ++e;
  const int lt = bx - tb[e];
  const int cnte = cnt[e];
  const int slot0 = off[e] + lt * 128;
  const int bn = blockIdx.y * 128;
  const int tid = threadIdx.x;
  const int wave = tid >> 6, lane = tid & 63;
  const int wr = (wave >> 1) * 64, wc = (wave & 1) * 64;
  const int l16 = lane & 15, quad = lane >> 4;
  __shared__ short As[128 * LDSP];
  __shared__ short Bs[128 * LDSP];
  __shared__ int stok[128];
  if (tid < 128) stok[tid] = (lt * 128 + tid < cnte) ? perm[slot0 + tid] : -1;
  __syncthreads();
  f32x4 acc[4][4] = {};
  const short* Wexp = w1t + (size_t)e * DD * HID;  // [HID][DD] bf16
  for (int k0 = 0; k0 < DD; k0 += 32) {
#pragma unroll
    for (int l = 0; l < 4; ++l) {
      int c = tid + l * 256, m = c >> 3, kq = c & 7;
      int tok = stok[m];
      s16x4 s; s.x = 0; s.y = 0; s.z = 0; s.w = 0;
      if (tok >= 0) {
        const float4 v = *(const float4*)(Aall + (size_t)tok * DD + k0 + kq * 4);
        s.x = f2bf(v.x); s.y = f2bf(v.y); s.z = f2bf(v.z); s.w = f2bf(v.w);
      }
      *(s16x4*)(&As[m * LDSP + kq * 4]) = s;
    }
#pragma unroll
    for (int l = 0; l < 2; ++l) {
      int c = tid + l * 256, n = c >> 2, kq = c & 3;
      *(s16x8*)(&Bs[n * LDSP + kq * 8]) = *(const s16x8*)(Wexp + (size_t)(bn + n) * DD + k0 + kq * 8);
    }
    __syncthreads();
    s16x8 af[4], bfr[4];
#pragma unroll
    for (int i = 0; i < 4; ++i) af[i] = *(s16x8*)(&As[(wr + i * 16 + l16) * LDSP + quad * 8]);
#pragma unroll
    for (int j = 0; j < 4; ++j) bfr[j] = *(s16x8*)(&Bs[(wc + j * 16 + l16) * LDSP + quad * 8]);
#pragma unroll
    for (int i = 0; i < 4; ++i)
#pragma unroll
      for (int j = 0; j < 4; ++j)
        acc[i][j] = __builtin_amdgcn_mfma_f32_16x16x32_bf16(af[i], bfr[j], acc[i][j], 0, 0, 0);
    __syncthreads();
  }
#pragma unroll
  for (int i = 0; i < 4; ++i) {
#pragma unroll
    for (int r = 0; r < 4; ++r) {
      int rl = wr + i * 16 + quad * 4 + r;
      if (lt * 128 + rl >= cnte) continue;
#pragma unroll
      for (int j = 0; j < 4; ++j) {
        int col = bn + wc + j * 16 + l16;
        float xv = acc[i][j][r] + b1[e * HID + col];
        float g = 0.5f * xv * (1.f + erff(xv * 0.70710678118654752f));
        hbuf[(size_t)(slot0 + rl) * HID + col] = f2bf(g);
      }
    }
  }
}

// ---------------- expert GEMM 2 (MFMA): out = x1 + gate*(h @ w2[e] + b2) ----------------
__global__ __launch_bounds__(256) void egemm2(const short* __restrict__ hbuf,
    const short* __restrict__ w2t, const float* __restrict__ b2,
    const int* __restrict__ perm, const int* __restrict__ off,
    const int* __restrict__ tb, const int* __restrict__ cnt,
    const float* __restrict__ gate, const float* __restrict__ x1,
    float* __restrict__ out) {
  const int bx = blockIdx.x;
  if (bx >= tb[EE]) return;
  int e = 0;
  while (e < EE - 1 && tb[e + 1] <= bx) ++e;
  const int lt = bx - tb[e];
  const int cnte = cnt[e];
  const int slot0 = off[e] + lt * 128;
  const int bn = blockIdx.y * 128;
  const int tid = threadIdx.x;
  const int wave = tid >> 6, lane = tid & 63;
  const int wr = (wave >> 1) * 64, wc = (wave & 1) * 64;
  const int l16 = lane & 15, quad = lane >> 4;
  __shared__ short As[128 * LDSP];
  __shared__ short Bs[128 * LDSP];
  __shared__ int stok[128];
  if (tid < 128) stok[tid] = (lt * 128 + tid < cnte) ? perm[slot0 + tid] : -1;
  __syncthreads();
  f32x4 acc[4][4] = {};
  const short* Wexp = w2t + (size_t)e * HID * DD;  // [DD][HID] bf16
  for (int k0 = 0; k0 < HID; k0 += 32) {
#pragma unroll
    for (int l = 0; l < 2; ++l) {
      int c = tid + l * 256, m = c >> 2, kq = c & 3;
      *(s16x8*)(&As[m * LDSP + kq * 8]) = *(const s16x8*)(hbuf + (size_t)(slot0 + m) * HID + k0 + kq * 8);
    }
#pragma unroll
    for (int l = 0; l < 2; ++l) {
      int c = tid + l * 256, n = c >> 2, kq = c & 3;
      *(s16x8*)(&Bs[n * LDSP + kq * 8]) = *(const s16x8*)(Wexp + (size_t)(bn + n) * HID + k0 + kq * 8);
    }
    __syncthreads();
    s16x8 af[4], bfr[4];
#pragma unroll
    for (int i = 0; i < 4; ++i) af[i] = *(s16x8*)(&As[(wr + i * 16 + l16) * LDSP + quad * 8]);
#pragma unroll
    for (int j = 0; j < 4; ++j) bfr[j] = *(s16x8*)(&Bs[(wc + j * 16 + l16) * LDSP + quad * 8]);
#pragma unroll
    for (int i = 0; i < 4; ++i)
#pragma unroll
      for (int j = 0; j < 4; ++j)
        acc[i][j] = __builtin_amdgcn_mfma_f32_16x16x32_bf16(af[i], bfr[j], acc[i][j], 0, 0, 0);
    __syncthreads();
  }
#pragma unroll
  for (int i = 0; i < 4; ++i) {
#pragma unroll
    for (int r = 0; r < 4; ++r) {
      int rl = wr + i * 16 + quad * 4 + r;
      if (lt * 128 + rl >= cnte) continue;
      int tok = stok[rl];
      float g = gate[tok];
#pragma unroll
      for (int j = 0; j < 4; ++j) {
        int col = bn + wc + j * 16 + l16;
        float val = acc[i][j][r] + b2[e * DD + col];
        out[(size_t)tok * DD + col] = x1[(size_t)tok * DD + col] + g * val;
      }
    }
  }
}

extern "C" void kernel_launch(void* const* d_in, const int* in_sizes, int n_in,
                              void* d_out, int out_size, void* d_ws, size_t ws_size,
                              hipStream_t stream) {
  const float* x     = (const float*)d_in[0];
  const float* ln1_w = (const float*)d_in[1];
  const float* ln1_b = (const float*)d_in[2];
  const float* wq    = (const float*)d_in[3];
  const float* bq    = (const float*)d_in[4];
  const float* wk    = (const float*)d_in[5];
  const float* bk    = (const float*)d_in[6];
  const float* wv    = (const float*)d_in[7];
  const float* bv    = (const float*)d_in[8];
  const float* wo    = (const float*)d_in[9];
  const float* bo    = (const float*)d_in[10];
  const float* ln2_w = (const float*)d_in[11];
  const float* ln2_b = (const float*)d_in[12];
  const float* wg    = (const float*)d_in[13];
  const float* bg    = (const float*)d_in[14];
  const float* w1    = (const float*)d_in[15];
  const float* b1    = (const float*)d_in[16];
  const float* w2    = (const float*)d_in[17];
  const float* b2    = (const float*)d_in[18];
  float* out = (float*)d_out;

  const size_t TD = (size_t)TT * DD;
  float* buf_ln  = (float*)d_ws;            // ln1 out, then ln2 out
  float* buf_q   = buf_ln + TD;             // q, then x1
  float* buf_att = buf_q + TD;              // attention output
  float* buf_kv  = buf_att + TD;            // [TT, 1536] fused k|v
  short* hbuf    = (short*)(buf_kv + (size_t)TT * KVSTR);       // [(TT+128), HID] bf16
  short* wqT     = hbuf + (size_t)(TT + 128) * HID;             // [768,768]
  short* kvT     = wqT + (size_t)DD * DD;                       // [1536,768]
  short* woT     = kvT + (size_t)KVSTR * DD;                    // [768,768]
  short* w1T     = woT + (size_t)DD * DD;                       // [E][3072,768]
  short* w2T     = w1T + (size_t)EE * DD * HID;                 // [E][768,3072]
  int*   meta    = (int*)(w2T + (size_t)EE * HID * DD);
  int*   idx     = meta;
  float* gate    = (float*)(meta + TT);
  int*   perm    = meta + 2 * TT;
  int*   cnt     = meta + 3 * TT;
  int*   off     = cnt + 8;
  int*   tb      = off + 9;
  int*   cur     = tb + 9;

  hipMemsetAsync(cnt, 0, 8 * sizeof(int), stream);

  // weight transposes (fp32 -> bf16 [N,K])
  transpose_bf16<<<dim3(12, 12, 1), 256, 0, stream>>>(wq, wqT, DD, DD);
  transpose_bf16<<<dim3(12, 12, 1), 256, 0, stream>>>(wk, kvT, DD, DD);
  transpose_bf16<<<dim3(12, 12, 1), 256, 0, stream>>>(wv, kvT + (size_t)DD * DD, DD, DD);
  transpose_bf16<<<dim3(12, 12, 1), 256, 0, stream>>>(wo, woT, DD, DD);
  transpose_bf16<<<dim3(12, 48, 8), 256, 0, stream>>>(w1, w1T, DD, HID);
  transpose_bf16<<<dim3(48, 12, 8), 256, 0, stream>>>(w2, w2T, HID, DD);

  ln_kernel<<<TT, 256, 0, stream>>>(x, ln1_w, ln1_b, buf_ln);

  mgemm<0><<<dim3(TT / 128, DD / 128), 256, 0, stream>>>(
      buf_ln, wqT, bq, nullptr, nullptr, buf_q, TT, DD, DD);
  mgemm<2><<<dim3(TT / 128, KVSTR / 128), 256, 0, stream>>>(
      x, kvT, bk, bv, nullptr, buf_kv, TT, KVSTR, DD);

  attn_kernel<<<dim3(SS / 64, BB, HH), 256, 0, stream>>>(
      buf_q, buf_kv, buf_kv + DD, buf_att);

  mgemm<1><<<dim3(TT / 128, DD / 128), 256, 0, stream>>>(
      buf_att, woT, bo, nullptr, x, buf_q, TT, DD, DD);   // x1

  ln_kernel<<<TT, 256, 0, stream>>>(buf_q, ln2_w, ln2_b, buf_ln);  // t_ln

  route_kernel<<<TT / 4, 256, 0, stream>>>(buf_ln, wg, bg, idx, gate, cnt);
  prefix_kernel<<<1, 64, 0, stream>>>(cnt, off, tb, cur);
  scatter_kernel<<<TT / 256, 256, 0, stream>>>(idx, off, cur, perm);

  egemm1<<<dim3(71, HID / 128), 256, 0, stream>>>(buf_ln, w1T, b1, perm, off, tb, cnt, hbuf);
  egemm2<<<dim3(71, DD / 128), 256, 0, stream>>>(hbuf, w2T, b2, perm, off, tb, cnt, gate, buf_q, out);
}

// Round 3
// 924.197 us; speedup vs baseline: 3.7086x; 1.2853x over previous
//
#include <hip/hip_runtime.h>
#include <math.h>

#define SS 512
#define BB 16
#define DD 768
#define HH 12
#define HDIM 64
#define EE 8
#define HID 3072
#define TT 8192   // SS*BB tokens
#define EPSV 1e-5f
#define KVSTR 1536
#define LDSP 40   // padded LDS row stride in shorts (80 B)
#define ASTR 72   // attention LDS row stride in shorts (144 B, 16B-aligned)

typedef __attribute__((ext_vector_type(8))) short s16x8;
typedef __attribute__((ext_vector_type(4))) short s16x4;
typedef __attribute__((ext_vector_type(4))) float f32x4;

__device__ inline short f2bf(float f) {
  unsigned u = __builtin_bit_cast(unsigned, f);
  unsigned r = (u + 0x7fffu + ((u >> 16) & 1u)) >> 16;
  return (short)r;
}

// ---------------- transpose + convert: W[K,N] fp32 -> Wt[N,K] bf16 ----------------
__global__ __launch_bounds__(256) void transpose_bf16(const float* __restrict__ W,
    short* __restrict__ Wt, int K, int N) {
  const float* Wz = W + (size_t)blockIdx.z * K * N;
  short* Wtz = Wt + (size_t)blockIdx.z * K * N;
  int k0 = blockIdx.x * 64, n0 = blockIdx.y * 64;
  __shared__ float t[64][65];
  for (int i = threadIdx.x; i < 4096; i += 256) {
    int r = i >> 6, c = i & 63;
    t[r][c] = Wz[(size_t)(k0 + r) * N + n0 + c];
  }
  __syncthreads();
  for (int i = threadIdx.x; i < 4096; i += 256) {
    int r = i >> 6, c = i & 63;
    Wtz[(size_t)(n0 + r) * K + k0 + c] = f2bf(t[c][r]);
  }
}

// ---------------- LayerNorm: one block per token ----------------
__global__ __launch_bounds__(256) void ln_kernel(const float* __restrict__ x,
    const float* __restrict__ w, const float* __restrict__ b, float* __restrict__ out) {
  int t = blockIdx.x, tid = threadIdx.x;
  const float* row = x + (size_t)t * DD;
  float s = 0.f, ss = 0.f;
  for (int i = tid; i < DD; i += 256) { float v = row[i]; s += v; ss += v * v; }
  for (int o = 32; o > 0; o >>= 1) { s += __shfl_down(s, o); ss += __shfl_down(ss, o); }
  __shared__ float sw[4], ssw[4];
  int wid = tid >> 6, lane = tid & 63;
  if (lane == 0) { sw[wid] = s; ssw[wid] = ss; }
  __syncthreads();
  if (tid == 0) {
    float s1 = sw[0] + sw[1] + sw[2] + sw[3];
    float s2 = ssw[0] + ssw[1] + ssw[2] + ssw[3];
    float mean = s1 / DD;
    float var = s2 / DD - mean * mean;
    sw[0] = mean; ssw[0] = rsqrtf(var + EPSV);
  }
  __syncthreads();
  float mean = sw[0], inv = ssw[0];
  float* orow = out + (size_t)t * DD;
  for (int i = tid; i < DD; i += 256) orow[i] = (row[i] - mean) * inv * w[i] + b[i];
}

// ---------------- bf16 MFMA GEMM: C = A@W^T(+bias)(+res) ----------------
template<int MODE>
__global__ __launch_bounds__(256) void mgemm(const float* __restrict__ A,
    const short* __restrict__ Wt, const float* __restrict__ bias,
    const float* __restrict__ bias2, const float* __restrict__ res,
    float* __restrict__ C, int M, int N, int K) {
  __shared__ short As[128 * LDSP];
  __shared__ short Bs[128 * LDSP];
  const int tid = threadIdx.x;
  const int wave = tid >> 6, lane = tid & 63;
  const int wr = (wave >> 1) * 64, wc = (wave & 1) * 64;
  const int l16 = lane & 15, quad = lane >> 4;
  const int bm = blockIdx.x * 128, bn = blockIdx.y * 128;
  f32x4 acc[4][4] = {};
  for (int k0 = 0; k0 < K; k0 += 32) {
#pragma unroll
    for (int l = 0; l < 4; ++l) {
      int c = tid + l * 256, m = c >> 3, kq = c & 7;
      const float4 v = *(const float4*)(A + (size_t)(bm + m) * K + k0 + kq * 4);
      s16x4 s; s.x = f2bf(v.x); s.y = f2bf(v.y); s.z = f2bf(v.z); s.w = f2bf(v.w);
      *(s16x4*)(&As[m * LDSP + kq * 4]) = s;
    }
#pragma unroll
    for (int l = 0; l < 2; ++l) {
      int c = tid + l * 256, n = c >> 2, kq = c & 3;
      *(s16x8*)(&Bs[n * LDSP + kq * 8]) = *(const s16x8*)(Wt + (size_t)(bn + n) * K + k0 + kq * 8);
    }
    __syncthreads();
    s16x8 af[4], bfr[4];
#pragma unroll
    for (int i = 0; i < 4; ++i) af[i] = *(s16x8*)(&As[(wr + i * 16 + l16) * LDSP + quad * 8]);
#pragma unroll
    for (int j = 0; j < 4; ++j) bfr[j] = *(s16x8*)(&Bs[(wc + j * 16 + l16) * LDSP + quad * 8]);
#pragma unroll
    for (int i = 0; i < 4; ++i)
#pragma unroll
      for (int j = 0; j < 4; ++j)
        acc[i][j] = __builtin_amdgcn_mfma_f32_16x16x32_bf16(af[i], bfr[j], acc[i][j], 0, 0, 0);
    __syncthreads();
  }
#pragma unroll
  for (int i = 0; i < 4; ++i) {
#pragma unroll
    for (int r = 0; r < 4; ++r) {
      int row = bm + wr + i * 16 + quad * 4 + r;
#pragma unroll
      for (int j = 0; j < 4; ++j) {
        int col = bn + wc + j * 16 + l16;
        float bv = (MODE == 2) ? (col >= DD ? bias2[col - DD] : bias[col]) : bias[col];
        float val = acc[i][j][r] + bv;
        if (MODE == 1) val += res[(size_t)row * N + col];
        C[(size_t)row * N + col] = val;
      }
    }
  }
}

// ---------------- flash attention, bf16 MFMA ----------------
// grid (SS/64, BB, HH). q fp32 [T,DD]; k,v fp32 strided KVSTR (v base pre-offset).
__global__ __launch_bounds__(256) void attn_mfma(const float* __restrict__ q,
    const float* __restrict__ k, const float* __restrict__ v, float* __restrict__ o) {
  const int qt = blockIdx.x, bidx = blockIdx.y, hidx = blockIdx.z;
  const int tid = threadIdx.x;
  const int wave = tid >> 6, lane = tid & 63;
  const int l16 = lane & 15, quad = lane >> 4;
  const int s0 = qt * 64;
  __shared__ short Qs[64 * ASTR];
  __shared__ short Ks[64 * ASTR];
  __shared__ short Vs[64 * ASTR];   // transposed: Vs[d][key]
  __shared__ short Ps[64 * ASTR];
  // stage Q (bf16, * 1/sqrt(HD))
  for (int i = tid; i < 1024; i += 256) {
    int r = i >> 4, c4 = i & 15;
    const float4 vq = *(const float4*)(q + ((size_t)(s0 + r) * BB + bidx) * DD + hidx * HDIM + c4 * 4);
    s16x4 s;
    s.x = f2bf(vq.x * 0.125f); s.y = f2bf(vq.y * 0.125f);
    s.z = f2bf(vq.z * 0.125f); s.w = f2bf(vq.w * 0.125f);
    *(s16x4*)(&Qs[r * ASTR + c4 * 4]) = s;
  }
  __syncthreads();
  s16x8 af0 = *(s16x8*)(&Qs[(wave * 16 + l16) * ASTR + quad * 8]);
  s16x8 af1 = *(s16x8*)(&Qs[(wave * 16 + l16) * ASTR + 32 + quad * 8]);
  f32x4 oacc[4] = {};
  float mr[4], lr[4];
#pragma unroll
  for (int r = 0; r < 4; ++r) { mr[r] = -1e30f; lr[r] = 0.f; }

  for (int t0 = 0; t0 < SS; t0 += 64) {
    __syncthreads();   // protect Ks/Vs from previous iteration's reads
    for (int i = tid; i < 1024; i += 256) {
      int r = i >> 4, c4 = i & 15;
      size_t base = ((size_t)(t0 + r) * BB + bidx) * KVSTR + hidx * HDIM + c4 * 4;
      const float4 vk = *(const float4*)(k + base);
      s16x4 sk;
      sk.x = f2bf(vk.x); sk.y = f2bf(vk.y); sk.z = f2bf(vk.z); sk.w = f2bf(vk.w);
      *(s16x4*)(&Ks[r * ASTR + c4 * 4]) = sk;
      const float4 vv = *(const float4*)(v + base);
      Vs[(c4 * 4 + 0) * ASTR + r] = f2bf(vv.x);
      Vs[(c4 * 4 + 1) * ASTR + r] = f2bf(vv.y);
      Vs[(c4 * 4 + 2) * ASTR + r] = f2bf(vv.z);
      Vs[(c4 * 4 + 3) * ASTR + r] = f2bf(vv.w);
    }
    __syncthreads();
    // S = Q @ K^T  (16 rows x 64 keys per wave)
    f32x4 sc[4];
    const f32x4 zero = {};
#pragma unroll
    for (int j = 0; j < 4; ++j) {
      s16x8 kf0 = *(s16x8*)(&Ks[(j * 16 + l16) * ASTR + quad * 8]);
      s16x8 kf1 = *(s16x8*)(&Ks[(j * 16 + l16) * ASTR + 32 + quad * 8]);
      sc[j] = __builtin_amdgcn_mfma_f32_16x16x32_bf16(af0, kf0, zero, 0, 0, 0);
      sc[j] = __builtin_amdgcn_mfma_f32_16x16x32_bf16(af1, kf1, sc[j], 0, 0, 0);
    }
    // online softmax: row = quad*4+r, distributed over 16 l16 lanes x 4 j-blocks
    float tm[4], alpha[4], rs[4];
#pragma unroll
    for (int r = 0; r < 4; ++r) {
      tm[r] = mr[r];
#pragma unroll
      for (int j = 0; j < 4; ++j) tm[r] = fmaxf(tm[r], sc[j][r]);
    }
#pragma unroll
    for (int mask = 1; mask < 16; mask <<= 1)
#pragma unroll
      for (int r = 0; r < 4; ++r) tm[r] = fmaxf(tm[r], __shfl_xor(tm[r], mask));
#pragma unroll
    for (int r = 0; r < 4; ++r) { alpha[r] = __expf(mr[r] - tm[r]); mr[r] = tm[r]; rs[r] = 0.f; }
#pragma unroll
    for (int j = 0; j < 4; ++j)
#pragma unroll
      for (int r = 0; r < 4; ++r) {
        float p = __expf(sc[j][r] - tm[r]);
        sc[j][r] = p; rs[r] += p;
      }
#pragma unroll
    for (int mask = 1; mask < 16; mask <<= 1)
#pragma unroll
      for (int r = 0; r < 4; ++r) rs[r] += __shfl_xor(rs[r], mask);
#pragma unroll
    for (int r = 0; r < 4; ++r) lr[r] = lr[r] * alpha[r] + rs[r];
    // P -> LDS (C-layout -> A-layout round trip)
#pragma unroll
    for (int j = 0; j < 4; ++j)
#pragma unroll
      for (int r = 0; r < 4; ++r)
        Ps[(wave * 16 + quad * 4 + r) * ASTR + j * 16 + l16] = f2bf(sc[j][r]);
    // rescale O
#pragma unroll
    for (int jd = 0; jd < 4; ++jd)
#pragma unroll
      for (int r = 0; r < 4; ++r) oacc[jd][r] *= alpha[r];
    __syncthreads();
    s16x8 pf0 = *(s16x8*)(&Ps[(wave * 16 + l16) * ASTR + quad * 8]);
    s16x8 pf1 = *(s16x8*)(&Ps[(wave * 16 + l16) * ASTR + 32 + quad * 8]);
#pragma unroll
    for (int jd = 0; jd < 4; ++jd) {
      s16x8 vf0 = *(s16x8*)(&Vs[(jd * 16 + l16) * ASTR + quad * 8]);
      s16x8 vf1 = *(s16x8*)(&Vs[(jd * 16 + l16) * ASTR + 32 + quad * 8]);
      oacc[jd] = __builtin_amdgcn_mfma_f32_16x16x32_bf16(pf0, vf0, oacc[jd], 0, 0, 0);
      oacc[jd] = __builtin_amdgcn_mfma_f32_16x16x32_bf16(pf1, vf1, oacc[jd], 0, 0, 0);
    }
  }
#pragma unroll
  for (int r = 0; r < 4; ++r) {
    int row = s0 + wave * 16 + quad * 4 + r;
    float invl = 1.f / lr[r];
#pragma unroll
    for (int jd = 0; jd < 4; ++jd) {
      int d = jd * 16 + l16;
      o[((size_t)row * BB + bidx) * DD + hidx * HDIM + d] = oacc[jd][r] * invl;
    }
  }
}

// ---------------- MoE routing ----------------
__global__ __launch_bounds__(256) void route_kernel(const float* __restrict__ tln,
    const float* __restrict__ wg, const float* __restrict__ bg,
    int* __restrict__ idx, float* __restrict__ gate, int* __restrict__ cnt) {
  int token = blockIdx.x * 4 + (threadIdx.x >> 6);
  int lane = threadIdx.x & 63;
  const float* row = tln + (size_t)token * DD;
  float acc[EE];
#pragma unroll
  for (int e = 0; e < EE; ++e) acc[e] = 0.f;
  for (int d = lane; d < DD; d += 64) {
    float tv = row[d];
#pragma unroll
    for (int e = 0; e < EE; ++e) acc[e] += tv * wg[d * EE + e];
  }
  for (int o = 32; o > 0; o >>= 1)
#pragma unroll
    for (int e = 0; e < EE; ++e) acc[e] += __shfl_down(acc[e], o);
  if (lane == 0) {
#pragma unroll
    for (int e = 0; e < EE; ++e) acc[e] += bg[e];
    int best = 0; float bm = acc[0];
#pragma unroll
    for (int e = 1; e < EE; ++e) if (acc[e] > bm) { bm = acc[e]; best = e; }
    float sum = 0.f;
#pragma unroll
    for (int e = 0; e < EE; ++e) sum += __expf(acc[e] - bm);
    idx[token] = best;
    gate[token] = 1.0f / sum;
    atomicAdd(&cnt[best], 1);
  }
}

__global__ void prefix_kernel(const int* __restrict__ cnt, int* __restrict__ off,
                              int* __restrict__ tb, int* __restrict__ cur) {
  if (threadIdx.x == 0 && blockIdx.x == 0) {
    int o = 0, t = 0;
    for (int e = 0; e < EE; ++e) {
      off[e] = o; tb[e] = t;
      o += cnt[e]; t += (cnt[e] + 127) >> 7;
      cur[e] = 0;
    }
    off[EE] = o; tb[EE] = t;
  }
}

__global__ __launch_bounds__(256) void scatter_kernel(const int* __restrict__ idx,
    const int* __restrict__ off, int* __restrict__ cur, int* __restrict__ perm) {
  int t = blockIdx.x * 256 + threadIdx.x;
  if (t < TT) {
    int e = idx[t];
    int p = atomicAdd(&cur[e], 1);
    perm[off[e] + p] = t;
  }
}

// ---------------- expert GEMM 1 (MFMA): h = gelu(t @ w1[e]) -> bf16 ----------------
__global__ __launch_bounds__(256) void egemm1(const float* __restrict__ Aall,
    const short* __restrict__ w1t, const float* __restrict__ b1,
    const int* __restrict__ perm, const int* __restrict__ off,
    const int* __restrict__ tb, const int* __restrict__ cnt,
    short* __restrict__ hbuf) {
  const int bx = blockIdx.x;
  if (bx >= tb[EE]) return;
  int e = 0;
  while (e < EE - 1 && tb[e + 1] <= bx) ++e;
  const int lt = bx - tb[e];
  const int cnte = cnt[e];
  const int slot0 = off[e] + lt * 128;
  const int bn = blockIdx.y * 128;
  const int tid = threadIdx.x;
  const int wave = tid >> 6, lane = tid & 63;
  const int wr = (wave >> 1) * 64, wc = (wave & 1) * 64;
  const int l16 = lane & 15, quad = lane >> 4;
  __shared__ short As[128 * LDSP];
  __shared__ short Bs[128 * LDSP];
  __shared__ int stok[128];
  if (tid < 128) stok[tid] = (lt * 128 + tid < cnte) ? perm[slot0 + tid] : -1;
  __syncthreads();
  f32x4 acc[4][4] = {};
  const short* Wexp = w1t + (size_t)e * DD * HID;  // [HID][DD] bf16
  for (int k0 = 0; k0 < DD; k0 += 32) {
#pragma unroll
    for (int l = 0; l < 4; ++l) {
      int c = tid + l * 256, m = c >> 3, kq = c & 7;
      int tok = stok[m];
      s16x4 s; s.x = 0; s.y = 0; s.z = 0; s.w = 0;
      if (tok >= 0) {
        const float4 v = *(const float4*)(Aall + (size_t)tok * DD + k0 + kq * 4);
        s.x = f2bf(v.x); s.y = f2bf(v.y); s.z = f2bf(v.z); s.w = f2bf(v.w);
      }
      *(s16x4*)(&As[m * LDSP + kq * 4]) = s;
    }
#pragma unroll
    for (int l = 0; l < 2; ++l) {
      int c = tid + l * 256, n = c >> 2, kq = c & 3;
      *(s16x8*)(&Bs[n * LDSP + kq * 8]) = *(const s16x8*)(Wexp + (size_t)(bn + n) * DD + k0 + kq * 8);
    }
    __syncthreads();
    s16x8 af[4], bfr[4];
#pragma unroll
    for (int i = 0; i < 4; ++i) af[i] = *(s16x8*)(&As[(wr + i * 16 + l16) * LDSP + quad * 8]);
#pragma unroll
    for (int j = 0; j < 4; ++j) bfr[j] = *(s16x8*)(&Bs[(wc + j * 16 + l16) * LDSP + quad * 8]);
#pragma unroll
    for (int i = 0; i < 4; ++i)
#pragma unroll
      for (int j = 0; j < 4; ++j)
        acc[i][j] = __builtin_amdgcn_mfma_f32_16x16x32_bf16(af[i], bfr[j], acc[i][j], 0, 0, 0);
    __syncthreads();
  }
#pragma unroll
  for (int i = 0; i < 4; ++i) {
#pragma unroll
    for (int r = 0; r < 4; ++r) {
      int rl = wr + i * 16 + quad * 4 + r;
      if (lt * 128 + rl >= cnte) continue;
#pragma unroll
      for (int j = 0; j < 4; ++j) {
        int col = bn + wc + j * 16 + l16;
        float xv = acc[i][j][r] + b1[e * HID + col];
        float g = 0.5f * xv * (1.f + erff(xv * 0.70710678118654752f));
        hbuf[(size_t)(slot0 + rl) * HID + col] = f2bf(g);
      }
    }
  }
}

// ---------------- expert GEMM 2 (MFMA): out = x1 + gate*(h @ w2[e] + b2) ----------------
__global__ __launch_bounds__(256) void egemm2(const short* __restrict__ hbuf,
    const short* __restrict__ w2t, const float* __restrict__ b2,
    const int* __restrict__ perm, const int* __restrict__ off,
    const int* __restrict__ tb, const int* __restrict__ cnt,
    const float* __restrict__ gate, const float* __restrict__ x1,
    float* __restrict__ out) {
  const int bx = blockIdx.x;
  if (bx >= tb[EE]) return;
  int e = 0;
  while (e < EE - 1 && tb[e + 1] <= bx) ++e;
  const int lt = bx - tb[e];
  const int cnte = cnt[e];
  const int slot0 = off[e] + lt * 128;
  const int bn = blockIdx.y * 128;
  const int tid = threadIdx.x;
  const int wave = tid >> 6, lane = tid & 63;
  const int wr = (wave >> 1) * 64, wc = (wave & 1) * 64;
  const int l16 = lane & 15, quad = lane >> 4;
  __shared__ short As[128 * LDSP];
  __shared__ short Bs[128 * LDSP];
  __shared__ int stok[128];
  if (tid < 128) stok[tid] = (lt * 128 + tid < cnte) ? perm[slot0 + tid] : -1;
  __syncthreads();
  f32x4 acc[4][4] = {};
  const short* Wexp = w2t + (size_t)e * HID * DD;  // [DD][HID] bf16
  for (int k0 = 0; k0 < HID; k0 += 32) {
#pragma unroll
    for (int l = 0; l < 2; ++l) {
      int c = tid + l * 256, m = c >> 2, kq = c & 3;
      *(s16x8*)(&As[m * LDSP + kq * 8]) = *(const s16x8*)(hbuf + (size_t)(slot0 + m) * HID + k0 + kq * 8);
    }
#pragma unroll
    for (int l = 0; l < 2; ++l) {
      int c = tid + l * 256, n = c >> 2, kq = c & 3;
      *(s16x8*)(&Bs[n * LDSP + kq * 8]) = *(const s16x8*)(Wexp + (size_t)(bn + n) * HID + k0 + kq * 8);
    }
    __syncthreads();
    s16x8 af[4], bfr[4];
#pragma unroll
    for (int i = 0; i < 4; ++i) af[i] = *(s16x8*)(&As[(wr + i * 16 + l16) * LDSP + quad * 8]);
#pragma unroll
    for (int j = 0; j < 4; ++j) bfr[j] = *(s16x8*)(&Bs[(wc + j * 16 + l16) * LDSP + quad * 8]);
#pragma unroll
    for (int i = 0; i < 4; ++i)
#pragma unroll
      for (int j = 0; j < 4; ++j)
        acc[i][j] = __builtin_amdgcn_mfma_f32_16x16x32_bf16(af[i], bfr[j], acc[i][j], 0, 0, 0);
    __syncthreads();
  }
#pragma unroll
  for (int i = 0; i < 4; ++i) {
#pragma unroll
    for (int r = 0; r < 4; ++r) {
      int rl = wr + i * 16 + quad * 4 + r;
      if (lt * 128 + rl >= cnte) continue;
      int tok = stok[rl];
      float g = gate[tok];
#pragma unroll
      for (int j = 0; j < 4; ++j) {
        int col = bn + wc + j * 16 + l16;
        float val = acc[i][j][r] + b2[e * DD + col];
        out[(size_t)tok * DD + col] = x1[(size_t)tok * DD + col] + g * val;
      }
    }
  }
}

extern "C" void kernel_launch(void* const* d_in, const int* in_sizes, int n_in,
                              void* d_out, int out_size, void* d_ws, size_t ws_size,
                              hipStream_t stream) {
  const float* x     = (const float*)d_in[0];
  const float* ln1_w = (const float*)d_in[1];
  const float* ln1_b = (const float*)d_in[2];
  const float* wq    = (const float*)d_in[3];
  const float* bq    = (const float*)d_in[4];
  const float* wk    = (const float*)d_in[5];
  const float* bk    = (const float*)d_in[6];
  const float* wv    = (const float*)d_in[7];
  const float* bv    = (const float*)d_in[8];
  const float* wo    = (const float*)d_in[9];
  const float* bo    = (const float*)d_in[10];
  const float* ln2_w = (const float*)d_in[11];
  const float* ln2_b = (const float*)d_in[12];
  const float* wg    = (const float*)d_in[13];
  const float* bg    = (const float*)d_in[14];
  const float* w1    = (const float*)d_in[15];
  const float* b1    = (const float*)d_in[16];
  const float* w2    = (const float*)d_in[17];
  const float* b2    = (const float*)d_in[18];
  float* out = (float*)d_out;

  const size_t TD = (size_t)TT * DD;
  float* buf_ln  = (float*)d_ws;            // ln1 out, then ln2 out
  float* buf_q   = buf_ln + TD;             // q, then x1
  float* buf_att = buf_q + TD;              // attention output
  float* buf_kv  = buf_att + TD;            // [TT, 1536] fused k|v
  short* hbuf    = (short*)(buf_kv + (size_t)TT * KVSTR);       // [(TT+128), HID] bf16
  short* wqT     = hbuf + (size_t)(TT + 128) * HID;             // [768,768]
  short* kvT     = wqT + (size_t)DD * DD;                       // [1536,768]
  short* woT     = kvT + (size_t)KVSTR * DD;                    // [768,768]
  short* w1T     = woT + (size_t)DD * DD;                       // [E][3072,768]
  short* w2T     = w1T + (size_t)EE * DD * HID;                 // [E][768,3072]
  int*   meta    = (int*)(w2T + (size_t)EE * HID * DD);
  int*   idx     = meta;
  float* gate    = (float*)(meta + TT);
  int*   perm    = meta + 2 * TT;
  int*   cnt     = meta + 3 * TT;
  int*   off     = cnt + 8;
  int*   tb      = off + 9;
  int*   cur     = tb + 9;

  hipMemsetAsync(cnt, 0, 8 * sizeof(int), stream);

  // weight transposes (fp32 -> bf16 [N,K])
  transpose_bf16<<<dim3(12, 12, 1), 256, 0, stream>>>(wq, wqT, DD, DD);
  transpose_bf16<<<dim3(12, 12, 1), 256, 0, stream>>>(wk, kvT, DD, DD);
  transpose_bf16<<<dim3(12, 12, 1), 256, 0, stream>>>(wv, kvT + (size_t)DD * DD, DD, DD);
  transpose_bf16<<<dim3(12, 12, 1), 256, 0, stream>>>(wo, woT, DD, DD);
  transpose_bf16<<<dim3(12, 48, 8), 256, 0, stream>>>(w1, w1T, DD, HID);
  transpose_bf16<<<dim3(48, 12, 8), 256, 0, stream>>>(w2, w2T, HID, DD);

  ln_kernel<<<TT, 256, 0, stream>>>(x, ln1_w, ln1_b, buf_ln);

  mgemm<0><<<dim3(TT / 128, DD / 128), 256, 0, stream>>>(
      buf_ln, wqT, bq, nullptr, nullptr, buf_q, TT, DD, DD);
  mgemm<2><<<dim3(TT / 128, KVSTR / 128), 256, 0, stream>>>(
      x, kvT, bk, bv, nullptr, buf_kv, TT, KVSTR, DD);

  attn_mfma<<<dim3(SS / 64, BB, HH), 256, 0, stream>>>(
      buf_q, buf_kv, buf_kv + DD, buf_att);

  mgemm<1><<<dim3(TT / 128, DD / 128), 256, 0, stream>>>(
      buf_att, woT, bo, nullptr, x, buf_q, TT, DD, DD);   // x1

  ln_kernel<<<TT, 256, 0, stream>>>(buf_q, ln2_w, ln2_b, buf_ln);  // t_ln

  route_kernel<<<TT / 4, 256, 0, stream>>>(buf_ln, wg, bg, idx, gate, cnt);
  prefix_kernel<<<1, 64, 0, stream>>>(cnt, off, tb, cur);
  scatter_kernel<<<TT / 256, 256, 0, stream>>>(idx, off, cur, perm);

  egemm1<<<dim3(71, HID / 128), 256, 0, stream>>>(buf_ln, w1T, b1, perm, off, tb, cnt, hbuf);
  egemm2<<<dim3(71, DD / 128), 256, 0, stream>>>(hbuf, w2T, b2, perm, off, tb, cnt, gate, buf_q, out);
}

// Round 4
// 810.589 us; speedup vs baseline: 4.2284x; 1.1402x over previous
//
#include <hip/hip_runtime.h>
#include <math.h>

#define SS 512
#define BB 16
#define DD 768
#define HH 12
#define HDIM 64
#define EE 8
#define HID 3072
#define TT 8192   // SS*BB tokens
#define EPSV 1e-5f
#define KVSTR 1536
#define LDSP 40   // padded LDS row stride in shorts (80 B)
#define ASTR 72   // attention LDS row stride in shorts (144 B, 16B-aligned)

typedef __attribute__((ext_vector_type(8))) short s16x8;
typedef __attribute__((ext_vector_type(4))) short s16x4;
typedef __attribute__((ext_vector_type(4))) float f32x4;

__device__ inline short f2bf(float f) {
  unsigned u = __builtin_bit_cast(unsigned, f);
  unsigned r = (u + 0x7fffu + ((u >> 16) & 1u)) >> 16;
  return (short)r;
}

// ---------------- fp32 -> bf16 bulk convert ----------------
__global__ __launch_bounds__(256) void convert_bf16(const float* __restrict__ src,
    short* __restrict__ dst) {
  size_t g = (size_t)blockIdx.x * 256 + threadIdx.x;
  const float4 v = *(const float4*)(src + g * 4);
  s16x4 s; s.x = f2bf(v.x); s.y = f2bf(v.y); s.z = f2bf(v.z); s.w = f2bf(v.w);
  *(s16x4*)(dst + g * 4) = s;
}

// ---------------- transpose + convert: W[K,N] fp32 -> Wt[N,K] bf16 ----------------
__global__ __launch_bounds__(256) void transpose_bf16(const float* __restrict__ W,
    short* __restrict__ Wt, int K, int N) {
  const float* Wz = W + (size_t)blockIdx.z * K * N;
  short* Wtz = Wt + (size_t)blockIdx.z * K * N;
  int k0 = blockIdx.x * 64, n0 = blockIdx.y * 64;
  __shared__ float t[64][65];
  for (int i = threadIdx.x; i < 4096; i += 256) {
    int r = i >> 6, c = i & 63;
    t[r][c] = Wz[(size_t)(k0 + r) * N + n0 + c];
  }
  __syncthreads();
  for (int i = threadIdx.x; i < 4096; i += 256) {
    int r = i >> 6, c = i & 63;
    Wtz[(size_t)(n0 + r) * K + k0 + c] = f2bf(t[c][r]);
  }
}

// ---------------- LayerNorm (bf16 out): one block per token ----------------
__global__ __launch_bounds__(256) void ln_kernel_bf(const float* __restrict__ x,
    const float* __restrict__ w, const float* __restrict__ b, short* __restrict__ out) {
  int t = blockIdx.x, tid = threadIdx.x;
  const float* row = x + (size_t)t * DD;
  float s = 0.f, ss = 0.f;
  for (int i = tid; i < DD; i += 256) { float v = row[i]; s += v; ss += v * v; }
  for (int o = 32; o > 0; o >>= 1) { s += __shfl_down(s, o); ss += __shfl_down(ss, o); }
  __shared__ float sw[4], ssw[4];
  int wid = tid >> 6, lane = tid & 63;
  if (lane == 0) { sw[wid] = s; ssw[wid] = ss; }
  __syncthreads();
  if (tid == 0) {
    float s1 = sw[0] + sw[1] + sw[2] + sw[3];
    float s2 = ssw[0] + ssw[1] + ssw[2] + ssw[3];
    float mean = s1 / DD;
    float var = s2 / DD - mean * mean;
    sw[0] = mean; ssw[0] = rsqrtf(var + EPSV);
  }
  __syncthreads();
  float mean = sw[0], inv = ssw[0];
  short* orow = out + (size_t)t * DD;
  for (int i = tid; i < DD; i += 256) orow[i] = f2bf((row[i] - mean) * inv * w[i] + b[i]);
}

// ---------------- LayerNorm (fp32 out) ----------------
__global__ __launch_bounds__(256) void ln_kernel(const float* __restrict__ x,
    const float* __restrict__ w, const float* __restrict__ b, float* __restrict__ out) {
  int t = blockIdx.x, tid = threadIdx.x;
  const float* row = x + (size_t)t * DD;
  float s = 0.f, ss = 0.f;
  for (int i = tid; i < DD; i += 256) { float v = row[i]; s += v; ss += v * v; }
  for (int o = 32; o > 0; o >>= 1) { s += __shfl_down(s, o); ss += __shfl_down(ss, o); }
  __shared__ float sw[4], ssw[4];
  int wid = tid >> 6, lane = tid & 63;
  if (lane == 0) { sw[wid] = s; ssw[wid] = ss; }
  __syncthreads();
  if (tid == 0) {
    float s1 = sw[0] + sw[1] + sw[2] + sw[3];
    float s2 = ssw[0] + ssw[1] + ssw[2] + ssw[3];
    float mean = s1 / DD;
    float var = s2 / DD - mean * mean;
    sw[0] = mean; ssw[0] = rsqrtf(var + EPSV);
  }
  __syncthreads();
  float mean = sw[0], inv = ssw[0];
  float* orow = out + (size_t)t * DD;
  for (int i = tid; i < DD; i += 256) orow[i] = (row[i] - mean) * inv * w[i] + b[i];
}

// ---------------- bf16 MFMA GEMM: C = A@W^T(+bias)(+res) ----------------
// A bf16 [M,K]; Wt bf16 [N,K]; 128x128 tile, BK=32, 4 waves of 64x64.
// 1-D grid, XCD-banded swizzle: rows-fastest within band.
// MODE 0: bias. MODE 1: bias + res(fp32). MODE 2: dual bias split at DD.
// OUTBF: 1 -> write bf16, 0 -> write fp32.
template<int MODE, int OUTBF>
__global__ __launch_bounds__(256) void mgemm(const short* __restrict__ A,
    const short* __restrict__ Wt, const float* __restrict__ bias,
    const float* __restrict__ bias2, const float* __restrict__ res,
    void* __restrict__ C, int N, int K) {
  const int bx = blockIdx.x;
  const int lid = bx >> 3;
  const int colt = lid >> 3, rband = lid & 7;
  const int bm = (((bx & 7) << 3) + rband) * 128;
  const int bn = colt * 128;
  __shared__ short As[128 * LDSP];
  __shared__ short Bs[128 * LDSP];
  const int tid = threadIdx.x;
  const int wave = tid >> 6, lane = tid & 63;
  const int wr = (wave >> 1) * 64, wc = (wave & 1) * 64;
  const int l16 = lane & 15, quad = lane >> 4;
  f32x4 acc[4][4] = {};
  for (int k0 = 0; k0 < K; k0 += 32) {
#pragma unroll
    for (int l = 0; l < 2; ++l) {
      int c = tid + l * 256, m = c >> 2, kq = c & 3;
      *(s16x8*)(&As[m * LDSP + kq * 8]) = *(const s16x8*)(A + (size_t)(bm + m) * K + k0 + kq * 8);
    }
#pragma unroll
    for (int l = 0; l < 2; ++l) {
      int c = tid + l * 256, n = c >> 2, kq = c & 3;
      *(s16x8*)(&Bs[n * LDSP + kq * 8]) = *(const s16x8*)(Wt + (size_t)(bn + n) * K + k0 + kq * 8);
    }
    __syncthreads();
    s16x8 af[4], bfr[4];
#pragma unroll
    for (int i = 0; i < 4; ++i) af[i] = *(s16x8*)(&As[(wr + i * 16 + l16) * LDSP + quad * 8]);
#pragma unroll
    for (int j = 0; j < 4; ++j) bfr[j] = *(s16x8*)(&Bs[(wc + j * 16 + l16) * LDSP + quad * 8]);
#pragma unroll
    for (int i = 0; i < 4; ++i)
#pragma unroll
      for (int j = 0; j < 4; ++j)
        acc[i][j] = __builtin_amdgcn_mfma_f32_16x16x32_bf16(af[i], bfr[j], acc[i][j], 0, 0, 0);
    __syncthreads();
  }
#pragma unroll
  for (int i = 0; i < 4; ++i) {
#pragma unroll
    for (int r = 0; r < 4; ++r) {
      int row = bm + wr + i * 16 + quad * 4 + r;
#pragma unroll
      for (int j = 0; j < 4; ++j) {
        int col = bn + wc + j * 16 + l16;
        float bv = (MODE == 2) ? (col >= DD ? bias2[col - DD] : bias[col]) : bias[col];
        float val = acc[i][j][r] + bv;
        if (MODE == 1) val += res[(size_t)row * N + col];
        if (OUTBF) ((short*)C)[(size_t)row * N + col] = f2bf(val);
        else       ((float*)C)[(size_t)row * N + col] = val;
      }
    }
  }
}

// ---------------- flash attention, bf16 MFMA, bf16 IO ----------------
// grid (SS/64, BB, HH). q bf16 [T,DD]; k,v bf16 strided KVSTR (v pre-offset).
__global__ __launch_bounds__(256) void attn_mfma(const short* __restrict__ q,
    const short* __restrict__ k, const short* __restrict__ v, short* __restrict__ o) {
  const int qt = blockIdx.x, bidx = blockIdx.y, hidx = blockIdx.z;
  const int tid = threadIdx.x;
  const int wave = tid >> 6, lane = tid & 63;
  const int l16 = lane & 15, quad = lane >> 4;
  const int s0 = qt * 64;
  __shared__ short Qs[64 * ASTR];
  __shared__ short Ks[64 * ASTR];
  __shared__ short Vs[64 * ASTR];   // transposed: Vs[d][key]
  __shared__ short Ps[64 * ASTR];
  for (int i = tid; i < 512; i += 256) {
    int r = i >> 3, c8 = i & 7;
    *(s16x8*)(&Qs[r * ASTR + c8 * 8]) =
        *(const s16x8*)(q + ((size_t)(s0 + r) * BB + bidx) * DD + hidx * HDIM + c8 * 8);
  }
  __syncthreads();
  s16x8 af0 = *(s16x8*)(&Qs[(wave * 16 + l16) * ASTR + quad * 8]);
  s16x8 af1 = *(s16x8*)(&Qs[(wave * 16 + l16) * ASTR + 32 + quad * 8]);
  f32x4 oacc[4] = {};
  float mr[4], lr[4];
#pragma unroll
  for (int r = 0; r < 4; ++r) { mr[r] = -1e30f; lr[r] = 0.f; }

  for (int t0 = 0; t0 < SS; t0 += 64) {
    __syncthreads();
    for (int i = tid; i < 512; i += 256) {
      int r = i >> 3, c8 = i & 7;
      *(s16x8*)(&Ks[r * ASTR + c8 * 8]) =
          *(const s16x8*)(k + ((size_t)(t0 + r) * BB + bidx) * KVSTR + hidx * HDIM + c8 * 8);
    }
    for (int i = tid; i < 1024; i += 256) {
      int r = i >> 4, c4 = i & 15;
      s16x4 vv = *(const s16x4*)(v + ((size_t)(t0 + r) * BB + bidx) * KVSTR + hidx * HDIM + c4 * 4);
      Vs[(c4 * 4 + 0) * ASTR + r] = vv.x;
      Vs[(c4 * 4 + 1) * ASTR + r] = vv.y;
      Vs[(c4 * 4 + 2) * ASTR + r] = vv.z;
      Vs[(c4 * 4 + 3) * ASTR + r] = vv.w;
    }
    __syncthreads();
    f32x4 sc[4];
    const f32x4 zero = {};
#pragma unroll
    for (int j = 0; j < 4; ++j) {
      s16x8 kf0 = *(s16x8*)(&Ks[(j * 16 + l16) * ASTR + quad * 8]);
      s16x8 kf1 = *(s16x8*)(&Ks[(j * 16 + l16) * ASTR + 32 + quad * 8]);
      sc[j] = __builtin_amdgcn_mfma_f32_16x16x32_bf16(af0, kf0, zero, 0, 0, 0);
      sc[j] = __builtin_amdgcn_mfma_f32_16x16x32_bf16(af1, kf1, sc[j], 0, 0, 0);
#pragma unroll
      for (int r = 0; r < 4; ++r) sc[j][r] *= 0.125f;   // 1/sqrt(HD) in fp32
    }
    float tm[4], alpha[4], rs[4];
#pragma unroll
    for (int r = 0; r < 4; ++r) {
      tm[r] = mr[r];
#pragma unroll
      for (int j = 0; j < 4; ++j) tm[r] = fmaxf(tm[r], sc[j][r]);
    }
#pragma unroll
    for (int mask = 1; mask < 16; mask <<= 1)
#pragma unroll
      for (int r = 0; r < 4; ++r) tm[r] = fmaxf(tm[r], __shfl_xor(tm[r], mask));
#pragma unroll
    for (int r = 0; r < 4; ++r) { alpha[r] = __expf(mr[r] - tm[r]); mr[r] = tm[r]; rs[r] = 0.f; }
#pragma unroll
    for (int j = 0; j < 4; ++j)
#pragma unroll
      for (int r = 0; r < 4; ++r) {
        float p = __expf(sc[j][r] - tm[r]);
        sc[j][r] = p; rs[r] += p;
      }
#pragma unroll
    for (int mask = 1; mask < 16; mask <<= 1)
#pragma unroll
      for (int r = 0; r < 4; ++r) rs[r] += __shfl_xor(rs[r], mask);
#pragma unroll
    for (int r = 0; r < 4; ++r) lr[r] = lr[r] * alpha[r] + rs[r];
#pragma unroll
    for (int j = 0; j < 4; ++j)
#pragma unroll
      for (int r = 0; r < 4; ++r)
        Ps[(wave * 16 + quad * 4 + r) * ASTR + j * 16 + l16] = f2bf(sc[j][r]);
#pragma unroll
    for (int jd = 0; jd < 4; ++jd)
#pragma unroll
      for (int r = 0; r < 4; ++r) oacc[jd][r] *= alpha[r];
    __syncthreads();
    s16x8 pf0 = *(s16x8*)(&Ps[(wave * 16 + l16) * ASTR + quad * 8]);
    s16x8 pf1 = *(s16x8*)(&Ps[(wave * 16 + l16) * ASTR + 32 + quad * 8]);
#pragma unroll
    for (int jd = 0; jd < 4; ++jd) {
      s16x8 vf0 = *(s16x8*)(&Vs[(jd * 16 + l16) * ASTR + quad * 8]);
      s16x8 vf1 = *(s16x8*)(&Vs[(jd * 16 + l16) * ASTR + 32 + quad * 8]);
      oacc[jd] = __builtin_amdgcn_mfma_f32_16x16x32_bf16(pf0, vf0, oacc[jd], 0, 0, 0);
      oacc[jd] = __builtin_amdgcn_mfma_f32_16x16x32_bf16(pf1, vf1, oacc[jd], 0, 0, 0);
    }
  }
#pragma unroll
  for (int r = 0; r < 4; ++r) {
    int row = s0 + wave * 16 + quad * 4 + r;
    float invl = 1.f / lr[r];
#pragma unroll
    for (int jd = 0; jd < 4; ++jd) {
      int d = jd * 16 + l16;
      o[((size_t)row * BB + bidx) * DD + hidx * HDIM + d] = f2bf(oacc[jd][r] * invl);
    }
  }
}

// ---------------- MoE routing (fp32 tln for argmax fidelity) ----------------
__global__ __launch_bounds__(256) void route_kernel(const float* __restrict__ tln,
    const float* __restrict__ wg, const float* __restrict__ bg,
    int* __restrict__ idx, float* __restrict__ gate, int* __restrict__ cnt) {
  int token = blockIdx.x * 4 + (threadIdx.x >> 6);
  int lane = threadIdx.x & 63;
  const float* row = tln + (size_t)token * DD;
  float acc[EE];
#pragma unroll
  for (int e = 0; e < EE; ++e) acc[e] = 0.f;
  for (int d = lane; d < DD; d += 64) {
    float tv = row[d];
#pragma unroll
    for (int e = 0; e < EE; ++e) acc[e] += tv * wg[d * EE + e];
  }
  for (int o = 32; o > 0; o >>= 1)
#pragma unroll
    for (int e = 0; e < EE; ++e) acc[e] += __shfl_down(acc[e], o);
  if (lane == 0) {
#pragma unroll
    for (int e = 0; e < EE; ++e) acc[e] += bg[e];
    int best = 0; float bm = acc[0];
#pragma unroll
    for (int e = 1; e < EE; ++e) if (acc[e] > bm) { bm = acc[e]; best = e; }
    float sum = 0.f;
#pragma unroll
    for (int e = 0; e < EE; ++e) sum += __expf(acc[e] - bm);
    idx[token] = best;
    gate[token] = 1.0f / sum;
    atomicAdd(&cnt[best], 1);
  }
}

__global__ void prefix_kernel(const int* __restrict__ cnt, int* __restrict__ off,
                              int* __restrict__ tb, int* __restrict__ cur) {
  if (threadIdx.x == 0 && blockIdx.x == 0) {
    int o = 0, t = 0;
    for (int e = 0; e < EE; ++e) {
      off[e] = o; tb[e] = t;
      o += cnt[e]; t += (cnt[e] + 127) >> 7;
      cur[e] = 0;
    }
    off[EE] = o; tb[EE] = t;
  }
}

__global__ __launch_bounds__(256) void scatter_kernel(const int* __restrict__ idx,
    const int* __restrict__ off, int* __restrict__ cur, int* __restrict__ perm) {
  int t = blockIdx.x * 256 + threadIdx.x;
  if (t < TT) {
    int e = idx[t];
    int p = atomicAdd(&cur[e], 1);
    perm[off[e] + p] = t;
  }
}

// ---------------- gather fp32 tln rows -> permuted bf16 A ----------------
// grid TT/8 blocks, 256 thr; block handles 8 slots, 32 lanes per slot.
__global__ __launch_bounds__(256) void gather_bf16(const float* __restrict__ tln,
    const int* __restrict__ perm, short* __restrict__ Abf) {
  int slot = blockIdx.x * 8 + (threadIdx.x >> 5);
  int l32 = threadIdx.x & 31;
  int tok = perm[slot];
  const float* src = tln + (size_t)tok * DD;
  short* dst = Abf + (size_t)slot * DD;
#pragma unroll
  for (int kk = 0; kk < 6; ++kk) {
    int base = kk * 128 + l32 * 4;
    const float4 vv = *(const float4*)(src + base);
    s16x4 s; s.x = f2bf(vv.x); s.y = f2bf(vv.y); s.z = f2bf(vv.z); s.w = f2bf(vv.w);
    *(s16x4*)(dst + base) = s;
  }
}

// ---------------- expert GEMM 1 (MFMA): h = gelu(Abf @ w1[e]) -> bf16 ----------------
// 1-D grid 8*9*24, XCD-banded, rows-fastest.
__global__ __launch_bounds__(256) void egemm1(const short* __restrict__ Abf,
    const short* __restrict__ w1t, const float* __restrict__ b1,
    const int* __restrict__ off, const int* __restrict__ tb, const int* __restrict__ cnt,
    short* __restrict__ hbuf) {
  const int bx = blockIdx.x;
  const int lid = bx >> 3;
  const int rband = lid % 9, colt = lid / 9;
  const int row = (bx & 7) * 9 + rband;
  if (row >= tb[EE]) return;
  int e = 0;
  while (e < EE - 1 && tb[e + 1] <= row) ++e;
  const int lt = row - tb[e];
  const int cnte = cnt[e];
  const int slot0 = off[e] + lt * 128;
  const int bn = colt * 128;
  const int tid = threadIdx.x;
  const int wave = tid >> 6, lane = tid & 63;
  const int wr = (wave >> 1) * 64, wc = (wave & 1) * 64;
  const int l16 = lane & 15, quad = lane >> 4;
  __shared__ short As[128 * LDSP];
  __shared__ short Bs[128 * LDSP];
  f32x4 acc[4][4] = {};
  const short* Aexp = Abf + (size_t)slot0 * DD;
  const short* Wexp = w1t + (size_t)e * DD * HID;  // [HID][DD] bf16
  for (int k0 = 0; k0 < DD; k0 += 32) {
#pragma unroll
    for (int l = 0; l < 2; ++l) {
      int c = tid + l * 256, m = c >> 2, kq = c & 3;
      *(s16x8*)(&As[m * LDSP + kq * 8]) = *(const s16x8*)(Aexp + (size_t)m * DD + k0 + kq * 8);
    }
#pragma unroll
    for (int l = 0; l < 2; ++l) {
      int c = tid + l * 256, n = c >> 2, kq = c & 3;
      *(s16x8*)(&Bs[n * LDSP + kq * 8]) = *(const s16x8*)(Wexp + (size_t)(bn + n) * DD + k0 + kq * 8);
    }
    __syncthreads();
    s16x8 af[4], bfr[4];
#pragma unroll
    for (int i = 0; i < 4; ++i) af[i] = *(s16x8*)(&As[(wr + i * 16 + l16) * LDSP + quad * 8]);
#pragma unroll
    for (int j = 0; j < 4; ++j) bfr[j] = *(s16x8*)(&Bs[(wc + j * 16 + l16) * LDSP + quad * 8]);
#pragma unroll
    for (int i = 0; i < 4; ++i)
#pragma unroll
      for (int j = 0; j < 4; ++j)
        acc[i][j] = __builtin_amdgcn_mfma_f32_16x16x32_bf16(af[i], bfr[j], acc[i][j], 0, 0, 0);
    __syncthreads();
  }
#pragma unroll
  for (int i = 0; i < 4; ++i) {
#pragma unroll
    for (int r = 0; r < 4; ++r) {
      int rl = wr + i * 16 + quad * 4 + r;
      if (lt * 128 + rl >= cnte) continue;
#pragma unroll
      for (int j = 0; j < 4; ++j) {
        int col = bn + wc + j * 16 + l16;
        float xv = acc[i][j][r] + b1[e * HID + col];
        float g = 0.5f * xv * (1.f + erff(xv * 0.70710678118654752f));
        hbuf[(size_t)(slot0 + rl) * HID + col] = f2bf(g);
      }
    }
  }
}

// ---------------- expert GEMM 2 (MFMA): out = x1 + gate*(h @ w2[e] + b2) ----------------
// 1-D grid 8*9*6, XCD-banded, cols-fastest (A-tile reuse across 6 cols).
__global__ __launch_bounds__(256) void egemm2(const short* __restrict__ hbuf,
    const short* __restrict__ w2t, const float* __restrict__ b2,
    const int* __restrict__ perm, const int* __restrict__ off,
    const int* __restrict__ tb, const int* __restrict__ cnt,
    const float* __restrict__ gate, const float* __restrict__ x1,
    float* __restrict__ out) {
  const int bx = blockIdx.x;
  const int lid = bx >> 3;
  const int colt = lid % 6, rband = lid / 6;
  const int row = (bx & 7) * 9 + rband;
  if (row >= tb[EE]) return;
  int e = 0;
  while (e < EE - 1 && tb[e + 1] <= row) ++e;
  const int lt = row - tb[e];
  const int cnte = cnt[e];
  const int slot0 = off[e] + lt * 128;
  const int bn = colt * 128;
  const int tid = threadIdx.x;
  const int wave = tid >> 6, lane = tid & 63;
  const int wr = (wave >> 1) * 64, wc = (wave & 1) * 64;
  const int l16 = lane & 15, quad = lane >> 4;
  __shared__ short As[128 * LDSP];
  __shared__ short Bs[128 * LDSP];
  __shared__ int stok[128];
  if (tid < 128) stok[tid] = (lt * 128 + tid < cnte) ? perm[slot0 + tid] : -1;
  __syncthreads();
  f32x4 acc[4][4] = {};
  const short* Wexp = w2t + (size_t)e * HID * DD;  // [DD][HID] bf16
  for (int k0 = 0; k0 < HID; k0 += 32) {
#pragma unroll
    for (int l = 0; l < 2; ++l) {
      int c = tid + l * 256, m = c >> 2, kq = c & 3;
      *(s16x8*)(&As[m * LDSP + kq * 8]) = *(const s16x8*)(hbuf + (size_t)(slot0 + m) * HID + k0 + kq * 8);
    }
#pragma unroll
    for (int l = 0; l < 2; ++l) {
      int c = tid + l * 256, n = c >> 2, kq = c & 3;
      *(s16x8*)(&Bs[n * LDSP + kq * 8]) = *(const s16x8*)(Wexp + (size_t)(bn + n) * HID + k0 + kq * 8);
    }
    __syncthreads();
    s16x8 af[4], bfr[4];
#pragma unroll
    for (int i = 0; i < 4; ++i) af[i] = *(s16x8*)(&As[(wr + i * 16 + l16) * LDSP + quad * 8]);
#pragma unroll
    for (int j = 0; j < 4; ++j) bfr[j] = *(s16x8*)(&Bs[(wc + j * 16 + l16) * LDSP + quad * 8]);
#pragma unroll
    for (int i = 0; i < 4; ++i)
#pragma unroll
      for (int j = 0; j < 4; ++j)
        acc[i][j] = __builtin_amdgcn_mfma_f32_16x16x32_bf16(af[i], bfr[j], acc[i][j], 0, 0, 0);
    __syncthreads();
  }
#pragma unroll
  for (int i = 0; i < 4; ++i) {
#pragma unroll
    for (int r = 0; r < 4; ++r) {
      int rl = wr + i * 16 + quad * 4 + r;
      if (lt * 128 + rl >= cnte) continue;
      int tok = stok[rl];
      float g = gate[tok];
#pragma unroll
      for (int j = 0; j < 4; ++j) {
        int col = bn + wc + j * 16 + l16;
        float val = acc[i][j][r] + b2[e * DD + col];
        out[(size_t)tok * DD + col] = x1[(size_t)tok * DD + col] + g * val;
      }
    }
  }
}

extern "C" void kernel_launch(void* const* d_in, const int* in_sizes, int n_in,
                              void* d_out, int out_size, void* d_ws, size_t ws_size,
                              hipStream_t stream) {
  const float* x     = (const float*)d_in[0];
  const float* ln1_w = (const float*)d_in[1];
  const float* ln1_b = (const float*)d_in[2];
  const float* wq    = (const float*)d_in[3];
  const float* bq    = (const float*)d_in[4];
  const float* wk    = (const float*)d_in[5];
  const float* bk    = (const float*)d_in[6];
  const float* wv    = (const float*)d_in[7];
  const float* bv    = (const float*)d_in[8];
  const float* wo    = (const float*)d_in[9];
  const float* bo    = (const float*)d_in[10];
  const float* ln2_w = (const float*)d_in[11];
  const float* ln2_b = (const float*)d_in[12];
  const float* wg    = (const float*)d_in[13];
  const float* bg    = (const float*)d_in[14];
  const float* w1    = (const float*)d_in[15];
  const float* b1    = (const float*)d_in[16];
  const float* w2    = (const float*)d_in[17];
  const float* b2    = (const float*)d_in[18];
  float* out = (float*)d_out;
  float* ws = (float*)d_ws;

  const size_t TD = (size_t)TT * DD;
  float* x1   = ws;                 // [TT,DD] fp32 (attn residual out)
  float* tln  = ws + TD;            // [TT,DD] fp32 (ln2 out, route input)
  short* sbase = (short*)(ws + 2 * TD);
  short* xbf   = sbase;                         // [TT,DD]; later reused as Abf
  short* Abf   = sbase;                         // alias (gather after xbf dead)
  short* ln1bf = sbase + TD + 128 * DD;         // [TT,DD]; later reused as attbf
  short* attbf = ln1bf;                         // alias (ln1bf dead after Q-proj)
  short* qbf   = ln1bf + TD;                    // [TT,DD]
  short* kvbf  = qbf + TD;                      // [TT,KVSTR]
  short* hbuf  = kvbf + (size_t)TT * KVSTR;     // [(TT+128),HID]
  short* wqT   = hbuf + (size_t)(TT + 128) * HID;
  short* kvT   = wqT + (size_t)DD * DD;
  short* woT   = kvT + (size_t)KVSTR * DD;
  short* w1T   = woT + (size_t)DD * DD;
  short* w2T   = w1T + (size_t)EE * DD * HID;
  int*   meta  = (int*)(w2T + (size_t)EE * HID * DD);
  int*   idx   = meta;
  float* gate  = (float*)(meta + TT);
  int*   perm  = meta + 2 * TT;
  int*   cnt   = meta + 3 * TT;
  int*   off   = cnt + 8;
  int*   tb    = off + 9;
  int*   cur   = tb + 9;

  hipMemsetAsync(cnt, 0, 8 * sizeof(int), stream);

  // weight transposes (fp32 -> bf16 [N,K])
  transpose_bf16<<<dim3(12, 12, 1), 256, 0, stream>>>(wq, wqT, DD, DD);
  transpose_bf16<<<dim3(12, 12, 1), 256, 0, stream>>>(wk, kvT, DD, DD);
  transpose_bf16<<<dim3(12, 12, 1), 256, 0, stream>>>(wv, kvT + (size_t)DD * DD, DD, DD);
  transpose_bf16<<<dim3(12, 12, 1), 256, 0, stream>>>(wo, woT, DD, DD);
  transpose_bf16<<<dim3(12, 48, 8), 256, 0, stream>>>(w1, w1T, DD, HID);
  transpose_bf16<<<dim3(48, 12, 8), 256, 0, stream>>>(w2, w2T, HID, DD);

  convert_bf16<<<TD / 1024, 256, 0, stream>>>(x, xbf);
  ln_kernel_bf<<<TT, 256, 0, stream>>>(x, ln1_w, ln1_b, ln1bf);

  mgemm<0, 1><<<64 * 6, 256, 0, stream>>>(ln1bf, wqT, bq, nullptr, nullptr, qbf, DD, DD);
  mgemm<2, 1><<<64 * 12, 256, 0, stream>>>(xbf, kvT, bk, bv, nullptr, kvbf, KVSTR, DD);

  attn_mfma<<<dim3(SS / 64, BB, HH), 256, 0, stream>>>(qbf, kvbf, kvbf + DD, attbf);

  mgemm<1, 0><<<64 * 6, 256, 0, stream>>>(attbf, woT, bo, nullptr, x, x1, DD, DD);

  ln_kernel<<<TT, 256, 0, stream>>>(x1, ln2_w, ln2_b, tln);

  route_kernel<<<TT / 4, 256, 0, stream>>>(tln, wg, bg, idx, gate, cnt);
  prefix_kernel<<<1, 64, 0, stream>>>(cnt, off, tb, cur);
  scatter_kernel<<<TT / 256, 256, 0, stream>>>(idx, off, cur, perm);
  gather_bf16<<<TT / 8, 256, 0, stream>>>(tln, perm, Abf);

  egemm1<<<8 * 9 * 24, 256, 0, stream>>>(Abf, w1T, b1, off, tb, cnt, hbuf);
  egemm2<<<8 * 9 * 6, 256, 0, stream>>>(hbuf, w2T, b2, perm, off, tb, cnt, gate, x1, out);
}

// Round 5
// 774.255 us; speedup vs baseline: 4.4268x; 1.0469x over previous
//
#include <hip/hip_runtime.h>
#include <math.h>

#define SS 512
#define BB 16
#define DD 768
#define HH 12
#define HDIM 64
#define EE 8
#define HID 3072
#define TT 8192   // SS*BB tokens
#define EPSV 1e-5f
#define KVSTR 1536
#define ASTR 72   // attention LDS row stride in shorts (144 B, 16B-aligned)

typedef __attribute__((ext_vector_type(8))) short s16x8;
typedef __attribute__((ext_vector_type(4))) short s16x4;
typedef __attribute__((ext_vector_type(4))) float f32x4;

__device__ inline short f2bf(float f) {
  unsigned u = __builtin_bit_cast(unsigned, f);
  unsigned r = (u + 0x7fffu + ((u >> 16) & 1u)) >> 16;
  return (short)r;
}

// async global->LDS DMA, 16B per lane; LDS dest = wave-uniform base + lane*16
__device__ inline void gl2lds16(const void* g, void* l) {
  __builtin_amdgcn_global_load_lds(
      (const __attribute__((address_space(1))) unsigned int*)g,
      (__attribute__((address_space(3))) unsigned int*)l, 16, 0, 0);
}

// ---------------- fp32 -> bf16 bulk convert ----------------
__global__ __launch_bounds__(256) void convert_bf16(const float* __restrict__ src,
    short* __restrict__ dst) {
  size_t g = (size_t)blockIdx.x * 256 + threadIdx.x;
  const float4 v = *(const float4*)(src + g * 4);
  s16x4 s; s.x = f2bf(v.x); s.y = f2bf(v.y); s.z = f2bf(v.z); s.w = f2bf(v.w);
  *(s16x4*)(dst + g * 4) = s;
}

// ---------------- transpose + convert: W[K,N] fp32 -> Wt[N,K] bf16 ----------------
__global__ __launch_bounds__(256) void transpose_bf16(const float* __restrict__ W,
    short* __restrict__ Wt, int K, int N) {
  const float* Wz = W + (size_t)blockIdx.z * K * N;
  short* Wtz = Wt + (size_t)blockIdx.z * K * N;
  int k0 = blockIdx.x * 64, n0 = blockIdx.y * 64;
  __shared__ float t[64][65];
  for (int i = threadIdx.x; i < 4096; i += 256) {
    int r = i >> 6, c = i & 63;
    t[r][c] = Wz[(size_t)(k0 + r) * N + n0 + c];
  }
  __syncthreads();
  for (int i = threadIdx.x; i < 4096; i += 256) {
    int r = i >> 6, c = i & 63;
    Wtz[(size_t)(n0 + r) * K + k0 + c] = f2bf(t[c][r]);
  }
}

// ---------------- LayerNorm (bf16 out) ----------------
__global__ __launch_bounds__(256) void ln_kernel_bf(const float* __restrict__ x,
    const float* __restrict__ w, const float* __restrict__ b, short* __restrict__ out) {
  int t = blockIdx.x, tid = threadIdx.x;
  const float* row = x + (size_t)t * DD;
  float s = 0.f, ss = 0.f;
  for (int i = tid; i < DD; i += 256) { float v = row[i]; s += v; ss += v * v; }
  for (int o = 32; o > 0; o >>= 1) { s += __shfl_down(s, o); ss += __shfl_down(ss, o); }
  __shared__ float sw[4], ssw[4];
  int wid = tid >> 6, lane = tid & 63;
  if (lane == 0) { sw[wid] = s; ssw[wid] = ss; }
  __syncthreads();
  if (tid == 0) {
    float s1 = sw[0] + sw[1] + sw[2] + sw[3];
    float s2 = ssw[0] + ssw[1] + ssw[2] + ssw[3];
    float mean = s1 / DD;
    float var = s2 / DD - mean * mean;
    sw[0] = mean; ssw[0] = rsqrtf(var + EPSV);
  }
  __syncthreads();
  float mean = sw[0], inv = ssw[0];
  short* orow = out + (size_t)t * DD;
  for (int i = tid; i < DD; i += 256) orow[i] = f2bf((row[i] - mean) * inv * w[i] + b[i]);
}

// ---------------- LayerNorm (fp32 out) ----------------
__global__ __launch_bounds__(256) void ln_kernel(const float* __restrict__ x,
    const float* __restrict__ w, const float* __restrict__ b, float* __restrict__ out) {
  int t = blockIdx.x, tid = threadIdx.x;
  const float* row = x + (size_t)t * DD;
  float s = 0.f, ss = 0.f;
  for (int i = tid; i < DD; i += 256) { float v = row[i]; s += v; ss += v * v; }
  for (int o = 32; o > 0; o >>= 1) { s += __shfl_down(s, o); ss += __shfl_down(ss, o); }
  __shared__ float sw[4], ssw[4];
  int wid = tid >> 6, lane = tid & 63;
  if (lane == 0) { sw[wid] = s; ssw[wid] = ss; }
  __syncthreads();
  if (tid == 0) {
    float s1 = sw[0] + sw[1] + sw[2] + sw[3];
    float s2 = ssw[0] + ssw[1] + ssw[2] + ssw[3];
    float mean = s1 / DD;
    float var = s2 / DD - mean * mean;
    sw[0] = mean; ssw[0] = rsqrtf(var + EPSV);
  }
  __syncthreads();
  float mean = sw[0], inv = ssw[0];
  float* orow = out + (size_t)t * DD;
  for (int i = tid; i < DD; i += 256) orow[i] = (row[i] - mean) * inv * w[i] + b[i];
}

// ---------------- bf16 MFMA GEMM, global_load_lds staging ----------------
// A bf16 [M,K]; Wt bf16 [N,K]; 128x128 tile, BK=32 (unpadded LDS rows, 64 B).
// MODE 0: bias. MODE 1: bias + res(fp32). MODE 2: dual bias split at DD.
template<int MODE, int OUTBF>
__global__ __launch_bounds__(256) void mgemm(const short* __restrict__ A,
    const short* __restrict__ Wt, const float* __restrict__ bias,
    const float* __restrict__ bias2, const float* __restrict__ res,
    void* __restrict__ C, int N, int K) {
  const int bx = blockIdx.x;
  const int lid = bx >> 3;
  const int colt = lid >> 3, rband = lid & 7;
  const int bm = (((bx & 7) << 3) + rband) * 128;
  const int bn = colt * 128;
  __shared__ short As[128 * 32];
  __shared__ short Bs[128 * 32];
  const int tid = threadIdx.x;
  const int wave = tid >> 6, lane = tid & 63;
  const int wr = (wave >> 1) * 64, wc = (wave & 1) * 64;
  const int l16 = lane & 15, quad = lane >> 4;
  const short* Ab = A + (size_t)(bm + (wave << 5) + (lane >> 2)) * K + ((lane & 3) << 3);
  const short* Bb = Wt + (size_t)(bn + (wave << 5) + (lane >> 2)) * K + ((lane & 3) << 3);
  short* lA = &As[(wave << 5) * 32];
  short* lB = &Bs[(wave << 5) * 32];
  f32x4 acc[4][4] = {};
  for (int k0 = 0; k0 < K; k0 += 32) {
    gl2lds16(Ab + k0, lA);
    gl2lds16(Ab + (size_t)16 * K + k0, lA + 512);
    gl2lds16(Bb + k0, lB);
    gl2lds16(Bb + (size_t)16 * K + k0, lB + 512);
    __syncthreads();
    s16x8 af[4], bfr[4];
#pragma unroll
    for (int i = 0; i < 4; ++i) af[i] = *(s16x8*)(&As[(wr + i * 16 + l16) * 32 + quad * 8]);
#pragma unroll
    for (int j = 0; j < 4; ++j) bfr[j] = *(s16x8*)(&Bs[(wc + j * 16 + l16) * 32 + quad * 8]);
#pragma unroll
    for (int i = 0; i < 4; ++i)
#pragma unroll
      for (int j = 0; j < 4; ++j)
        acc[i][j] = __builtin_amdgcn_mfma_f32_16x16x32_bf16(af[i], bfr[j], acc[i][j], 0, 0, 0);
    __syncthreads();
  }
#pragma unroll
  for (int i = 0; i < 4; ++i) {
#pragma unroll
    for (int r = 0; r < 4; ++r) {
      int row = bm + wr + i * 16 + quad * 4 + r;
#pragma unroll
      for (int j = 0; j < 4; ++j) {
        int col = bn + wc + j * 16 + l16;
        float bv = (MODE == 2) ? (col >= DD ? bias2[col - DD] : bias[col]) : bias[col];
        float val = acc[i][j][r] + bv;
        if (MODE == 1) val += res[(size_t)row * N + col];
        if (OUTBF) ((short*)C)[(size_t)row * N + col] = f2bf(val);
        else       ((float*)C)[(size_t)row * N + col] = val;
      }
    }
  }
}

// ---------------- flash attention, bf16 MFMA, bf16 IO ----------------
__global__ __launch_bounds__(256) void attn_mfma(const short* __restrict__ q,
    const short* __restrict__ k, const short* __restrict__ v, short* __restrict__ o) {
  const int qt = blockIdx.x, bidx = blockIdx.y, hidx = blockIdx.z;
  const int tid = threadIdx.x;
  const int wave = tid >> 6, lane = tid & 63;
  const int l16 = lane & 15, quad = lane >> 4;
  const int s0 = qt * 64;
  __shared__ short Qs[64 * ASTR];
  __shared__ short Ks[64 * ASTR];
  __shared__ short Vs[64 * ASTR];   // transposed: Vs[d][key]
  __shared__ short Ps[64 * ASTR];
  for (int i = tid; i < 512; i += 256) {
    int r = i >> 3, c8 = i & 7;
    *(s16x8*)(&Qs[r * ASTR + c8 * 8]) =
        *(const s16x8*)(q + ((size_t)(s0 + r) * BB + bidx) * DD + hidx * HDIM + c8 * 8);
  }
  __syncthreads();
  s16x8 af0 = *(s16x8*)(&Qs[(wave * 16 + l16) * ASTR + quad * 8]);
  s16x8 af1 = *(s16x8*)(&Qs[(wave * 16 + l16) * ASTR + 32 + quad * 8]);
  f32x4 oacc[4] = {};
  float mr[4], lr[4];
#pragma unroll
  for (int r = 0; r < 4; ++r) { mr[r] = -1e30f; lr[r] = 0.f; }

  for (int t0 = 0; t0 < SS; t0 += 64) {
    __syncthreads();
    for (int i = tid; i < 512; i += 256) {
      int r = i >> 3, c8 = i & 7;
      *(s16x8*)(&Ks[r * ASTR + c8 * 8]) =
          *(const s16x8*)(k + ((size_t)(t0 + r) * BB + bidx) * KVSTR + hidx * HDIM + c8 * 8);
    }
    for (int i = tid; i < 1024; i += 256) {
      int r = i >> 4, c4 = i & 15;
      s16x4 vv = *(const s16x4*)(v + ((size_t)(t0 + r) * BB + bidx) * KVSTR + hidx * HDIM + c4 * 4);
      Vs[(c4 * 4 + 0) * ASTR + r] = vv.x;
      Vs[(c4 * 4 + 1) * ASTR + r] = vv.y;
      Vs[(c4 * 4 + 2) * ASTR + r] = vv.z;
      Vs[(c4 * 4 + 3) * ASTR + r] = vv.w;
    }
    __syncthreads();
    f32x4 sc[4];
    const f32x4 zero = {};
#pragma unroll
    for (int j = 0; j < 4; ++j) {
      s16x8 kf0 = *(s16x8*)(&Ks[(j * 16 + l16) * ASTR + quad * 8]);
      s16x8 kf1 = *(s16x8*)(&Ks[(j * 16 + l16) * ASTR + 32 + quad * 8]);
      sc[j] = __builtin_amdgcn_mfma_f32_16x16x32_bf16(af0, kf0, zero, 0, 0, 0);
      sc[j] = __builtin_amdgcn_mfma_f32_16x16x32_bf16(af1, kf1, sc[j], 0, 0, 0);
#pragma unroll
      for (int r = 0; r < 4; ++r) sc[j][r] *= 0.125f;
    }
    float tm[4], alpha[4], rs[4];
#pragma unroll
    for (int r = 0; r < 4; ++r) {
      tm[r] = mr[r];
#pragma unroll
      for (int j = 0; j < 4; ++j) tm[r] = fmaxf(tm[r], sc[j][r]);
    }
#pragma unroll
    for (int mask = 1; mask < 16; mask <<= 1)
#pragma unroll
      for (int r = 0; r < 4; ++r) tm[r] = fmaxf(tm[r], __shfl_xor(tm[r], mask));
#pragma unroll
    for (int r = 0; r < 4; ++r) { alpha[r] = __expf(mr[r] - tm[r]); mr[r] = tm[r]; rs[r] = 0.f; }
#pragma unroll
    for (int j = 0; j < 4; ++j)
#pragma unroll
      for (int r = 0; r < 4; ++r) {
        float p = __expf(sc[j][r] - tm[r]);
        sc[j][r] = p; rs[r] += p;
      }
#pragma unroll
    for (int mask = 1; mask < 16; mask <<= 1)
#pragma unroll
      for (int r = 0; r < 4; ++r) rs[r] += __shfl_xor(rs[r], mask);
#pragma unroll
    for (int r = 0; r < 4; ++r) lr[r] = lr[r] * alpha[r] + rs[r];
#pragma unroll
    for (int j = 0; j < 4; ++j)
#pragma unroll
      for (int r = 0; r < 4; ++r)
        Ps[(wave * 16 + quad * 4 + r) * ASTR + j * 16 + l16] = f2bf(sc[j][r]);
#pragma unroll
    for (int jd = 0; jd < 4; ++jd)
#pragma unroll
      for (int r = 0; r < 4; ++r) oacc[jd][r] *= alpha[r];
    __syncthreads();
    s16x8 pf0 = *(s16x8*)(&Ps[(wave * 16 + l16) * ASTR + quad * 8]);
    s16x8 pf1 = *(s16x8*)(&Ps[(wave * 16 + l16) * ASTR + 32 + quad * 8]);
#pragma unroll
    for (int jd = 0; jd < 4; ++jd) {
      s16x8 vf0 = *(s16x8*)(&Vs[(jd * 16 + l16) * ASTR + quad * 8]);
      s16x8 vf1 = *(s16x8*)(&Vs[(jd * 16 + l16) * ASTR + 32 + quad * 8]);
      oacc[jd] = __builtin_amdgcn_mfma_f32_16x16x32_bf16(pf0, vf0, oacc[jd], 0, 0, 0);
      oacc[jd] = __builtin_amdgcn_mfma_f32_16x16x32_bf16(pf1, vf1, oacc[jd], 0, 0, 0);
    }
  }
#pragma unroll
  for (int r = 0; r < 4; ++r) {
    int row = s0 + wave * 16 + quad * 4 + r;
    float invl = 1.f / lr[r];
#pragma unroll
    for (int jd = 0; jd < 4; ++jd) {
      int d = jd * 16 + l16;
      o[((size_t)row * BB + bidx) * DD + hidx * HDIM + d] = f2bf(oacc[jd][r] * invl);
    }
  }
}

// ---------------- MoE routing ----------------
__global__ __launch_bounds__(256) void route_kernel(const float* __restrict__ tln,
    const float* __restrict__ wg, const float* __restrict__ bg,
    int* __restrict__ idx, float* __restrict__ gate, int* __restrict__ cnt) {
  int token = blockIdx.x * 4 + (threadIdx.x >> 6);
  int lane = threadIdx.x & 63;
  const float* row = tln + (size_t)token * DD;
  float acc[EE];
#pragma unroll
  for (int e = 0; e < EE; ++e) acc[e] = 0.f;
  for (int d = lane; d < DD; d += 64) {
    float tv = row[d];
#pragma unroll
    for (int e = 0; e < EE; ++e) acc[e] += tv * wg[d * EE + e];
  }
  for (int o = 32; o > 0; o >>= 1)
#pragma unroll
    for (int e = 0; e < EE; ++e) acc[e] += __shfl_down(acc[e], o);
  if (lane == 0) {
#pragma unroll
    for (int e = 0; e < EE; ++e) acc[e] += bg[e];
    int best = 0; float bm = acc[0];
#pragma unroll
    for (int e = 1; e < EE; ++e) if (acc[e] > bm) { bm = acc[e]; best = e; }
    float sum = 0.f;
#pragma unroll
    for (int e = 0; e < EE; ++e) sum += __expf(acc[e] - bm);
    idx[token] = best;
    gate[token] = 1.0f / sum;
    atomicAdd(&cnt[best], 1);
  }
}

__global__ void prefix_kernel(const int* __restrict__ cnt, int* __restrict__ off,
                              int* __restrict__ tb, int* __restrict__ cur) {
  if (threadIdx.x == 0 && blockIdx.x == 0) {
    int o = 0, t = 0;
    for (int e = 0; e < EE; ++e) {
      off[e] = o; tb[e] = t;
      o += cnt[e]; t += (cnt[e] + 127) >> 7;
      cur[e] = 0;
    }
    off[EE] = o; tb[EE] = t;
  }
}

__global__ __launch_bounds__(256) void scatter_kernel(const int* __restrict__ idx,
    const int* __restrict__ off, int* __restrict__ cur, int* __restrict__ perm) {
  int t = blockIdx.x * 256 + threadIdx.x;
  if (t < TT) {
    int e = idx[t];
    int p = atomicAdd(&cur[e], 1);
    perm[off[e] + p] = t;
  }
}

// ---------------- gather fp32 tln rows -> permuted bf16 A ----------------
__global__ __launch_bounds__(256) void gather_bf16(const float* __restrict__ tln,
    const int* __restrict__ perm, short* __restrict__ Abf) {
  int slot = blockIdx.x * 8 + (threadIdx.x >> 5);
  int l32 = threadIdx.x & 31;
  int tok = perm[slot];
  const float* src = tln + (size_t)tok * DD;
  short* dst = Abf + (size_t)slot * DD;
#pragma unroll
  for (int kk = 0; kk < 6; ++kk) {
    int base = kk * 128 + l32 * 4;
    const float4 vv = *(const float4*)(src + base);
    s16x4 s; s.x = f2bf(vv.x); s.y = f2bf(vv.y); s.z = f2bf(vv.z); s.w = f2bf(vv.w);
    *(s16x4*)(dst + base) = s;
  }
}

// ---------------- expert GEMM 1: h = gelu(Abf @ w1[e]) -> bf16 ----------------
__global__ __launch_bounds__(256) void egemm1(const short* __restrict__ Abf,
    const short* __restrict__ w1t, const float* __restrict__ b1,
    const int* __restrict__ off, const int* __restrict__ tb, const int* __restrict__ cnt,
    short* __restrict__ hbuf) {
  const int bx = blockIdx.x;
  const int lid = bx >> 3;
  const int rband = lid % 9, colt = lid / 9;
  const int row = (bx & 7) * 9 + rband;
  if (row >= tb[EE]) return;
  int e = 0;
  while (e < EE - 1 && tb[e + 1] <= row) ++e;
  const int lt = row - tb[e];
  const int cnte = cnt[e];
  const int slot0 = off[e] + lt * 128;
  const int bn = colt * 128;
  const int tid = threadIdx.x;
  const int wave = tid >> 6, lane = tid & 63;
  const int wr = (wave >> 1) * 64, wc = (wave & 1) * 64;
  const int l16 = lane & 15, quad = lane >> 4;
  __shared__ short As[128 * 32];
  __shared__ short Bs[128 * 32];
  f32x4 acc[4][4] = {};
  const short* Ab = Abf + (size_t)(slot0 + (wave << 5) + (lane >> 2)) * DD + ((lane & 3) << 3);
  const short* Bb = w1t + (size_t)e * DD * HID
                  + (size_t)(bn + (wave << 5) + (lane >> 2)) * DD + ((lane & 3) << 3);
  short* lA = &As[(wave << 5) * 32];
  short* lB = &Bs[(wave << 5) * 32];
  for (int k0 = 0; k0 < DD; k0 += 32) {
    gl2lds16(Ab + k0, lA);
    gl2lds16(Ab + (size_t)16 * DD + k0, lA + 512);
    gl2lds16(Bb + k0, lB);
    gl2lds16(Bb + (size_t)16 * DD + k0, lB + 512);
    __syncthreads();
    s16x8 af[4], bfr[4];
#pragma unroll
    for (int i = 0; i < 4; ++i) af[i] = *(s16x8*)(&As[(wr + i * 16 + l16) * 32 + quad * 8]);
#pragma unroll
    for (int j = 0; j < 4; ++j) bfr[j] = *(s16x8*)(&Bs[(wc + j * 16 + l16) * 32 + quad * 8]);
#pragma unroll
    for (int i = 0; i < 4; ++i)
#pragma unroll
      for (int j = 0; j < 4; ++j)
        acc[i][j] = __builtin_amdgcn_mfma_f32_16x16x32_bf16(af[i], bfr[j], acc[i][j], 0, 0, 0);
    __syncthreads();
  }
#pragma unroll
  for (int i = 0; i < 4; ++i) {
#pragma unroll
    for (int r = 0; r < 4; ++r) {
      int rl = wr + i * 16 + quad * 4 + r;
      if (lt * 128 + rl >= cnte) continue;
#pragma unroll
      for (int j = 0; j < 4; ++j) {
        int col = bn + wc + j * 16 + l16;
        float xv = acc[i][j][r] + b1[e * HID + col];
        float g = 0.5f * xv * (1.f + erff(xv * 0.70710678118654752f));
        hbuf[(size_t)(slot0 + rl) * HID + col] = f2bf(g);
      }
    }
  }
}

// ---------------- expert GEMM 2: out = x1 + gate*(h @ w2[e] + b2) ----------------
__global__ __launch_bounds__(256) void egemm2(const short* __restrict__ hbuf,
    const short* __restrict__ w2t, const float* __restrict__ b2,
    const int* __restrict__ perm, const int* __restrict__ off,
    const int* __restrict__ tb, const int* __restrict__ cnt,
    const float* __restrict__ gate, const float* __restrict__ x1,
    float* __restrict__ out) {
  const int bx = blockIdx.x;
  const int lid = bx >> 3;
  const int colt = lid % 6, rband = lid / 6;
  const int row = (bx & 7) * 9 + rband;
  if (row >= tb[EE]) return;
  int e = 0;
  while (e < EE - 1 && tb[e + 1] <= row) ++e;
  const int lt = row - tb[e];
  const int cnte = cnt[e];
  const int slot0 = off[e] + lt * 128;
  const int bn = colt * 128;
  const int tid = threadIdx.x;
  const int wave = tid >> 6, lane = tid & 63;
  const int wr = (wave >> 1) * 64, wc = (wave & 1) * 64;
  const int l16 = lane & 15, quad = lane >> 4;
  __shared__ short As[128 * 32];
  __shared__ short Bs[128 * 32];
  __shared__ int stok[128];
  if (tid < 128) stok[tid] = (lt * 128 + tid < cnte) ? perm[slot0 + tid] : -1;
  f32x4 acc[4][4] = {};
  const short* Ab = hbuf + (size_t)(slot0 + (wave << 5) + (lane >> 2)) * HID + ((lane & 3) << 3);
  const short* Bb = w2t + (size_t)e * HID * DD
                  + (size_t)(bn + (wave << 5) + (lane >> 2)) * HID + ((lane & 3) << 3);
  short* lA = &As[(wave << 5) * 32];
  short* lB = &Bs[(wave << 5) * 32];
  for (int k0 = 0; k0 < HID; k0 += 32) {
    gl2lds16(Ab + k0, lA);
    gl2lds16(Ab + (size_t)16 * HID + k0, lA + 512);
    gl2lds16(Bb + k0, lB);
    gl2lds16(Bb + (size_t)16 * HID + k0, lB + 512);
    __syncthreads();
    s16x8 af[4], bfr[4];
#pragma unroll
    for (int i = 0; i < 4; ++i) af[i] = *(s16x8*)(&As[(wr + i * 16 + l16) * 32 + quad * 8]);
#pragma unroll
    for (int j = 0; j < 4; ++j) bfr[j] = *(s16x8*)(&Bs[(wc + j * 16 + l16) * 32 + quad * 8]);
#pragma unroll
    for (int i = 0; i < 4; ++i)
#pragma unroll
      for (int j = 0; j < 4; ++j)
        acc[i][j] = __builtin_amdgcn_mfma_f32_16x16x32_bf16(af[i], bfr[j], acc[i][j], 0, 0, 0);
    __syncthreads();
  }
#pragma unroll
  for (int i = 0; i < 4; ++i) {
#pragma unroll
    for (int r = 0; r < 4; ++r) {
      int rl = wr + i * 16 + quad * 4 + r;
      if (lt * 128 + rl >= cnte) continue;
      int tok = stok[rl];
      float g = gate[tok];
#pragma unroll
      for (int j = 0; j < 4; ++j) {
        int col = bn + wc + j * 16 + l16;
        float val = acc[i][j][r] + b2[e * DD + col];
        out[(size_t)tok * DD + col] = x1[(size_t)tok * DD + col] + g * val;
      }
    }
  }
}

extern "C" void kernel_launch(void* const* d_in, const int* in_sizes, int n_in,
                              void* d_out, int out_size, void* d_ws, size_t ws_size,
                              hipStream_t stream) {
  const float* x     = (const float*)d_in[0];
  const float* ln1_w = (const float*)d_in[1];
  const float* ln1_b = (const float*)d_in[2];
  const float* wq    = (const float*)d_in[3];
  const float* bq    = (const float*)d_in[4];
  const float* wk    = (const float*)d_in[5];
  const float* bk    = (const float*)d_in[6];
  const float* wv    = (const float*)d_in[7];
  const float* bv    = (const float*)d_in[8];
  const float* wo    = (const float*)d_in[9];
  const float* bo    = (const float*)d_in[10];
  const float* ln2_w = (const float*)d_in[11];
  const float* ln2_b = (const float*)d_in[12];
  const float* wg    = (const float*)d_in[13];
  const float* bg    = (const float*)d_in[14];
  const float* w1    = (const float*)d_in[15];
  const float* b1    = (const float*)d_in[16];
  const float* w2    = (const float*)d_in[17];
  const float* b2    = (const float*)d_in[18];
  float* out = (float*)d_out;
  float* ws = (float*)d_ws;

  const size_t TD = (size_t)TT * DD;
  float* x1   = ws;                 // [TT,DD] fp32 (attn residual out)
  float* tln  = ws + TD;            // [TT,DD] fp32 (ln2 out, route input)
  short* sbase = (short*)(ws + 2 * TD);
  short* xbf   = sbase;                         // [TT,DD]; later reused as Abf
  short* Abf   = sbase;                         // alias (gather after xbf dead)
  short* ln1bf = sbase + TD + 128 * DD;         // [TT,DD]; later reused as attbf
  short* attbf = ln1bf;                         // alias (ln1bf dead after Q-proj)
  short* qbf   = ln1bf + TD;                    // [TT,DD]
  short* kvbf  = qbf + TD;                      // [TT,KVSTR]
  short* hbuf  = kvbf + (size_t)TT * KVSTR;     // [(TT+128),HID]
  short* wqT   = hbuf + (size_t)(TT + 128) * HID;
  short* kvT   = wqT + (size_t)DD * DD;
  short* woT   = kvT + (size_t)KVSTR * DD;
  short* w1T   = woT + (size_t)DD * DD;
  short* w2T   = w1T + (size_t)EE * DD * HID;
  int*   meta  = (int*)(w2T + (size_t)EE * HID * DD);
  int*   idx   = meta;
  float* gate  = (float*)(meta + TT);
  int*   perm  = meta + 2 * TT;
  int*   cnt   = meta + 3 * TT;
  int*   off   = cnt + 8;
  int*   tb    = off + 9;
  int*   cur   = tb + 9;

  hipMemsetAsync(cnt, 0, 8 * sizeof(int), stream);

  // weight transposes (fp32 -> bf16 [N,K])
  transpose_bf16<<<dim3(12, 12, 1), 256, 0, stream>>>(wq, wqT, DD, DD);
  transpose_bf16<<<dim3(12, 12, 1), 256, 0, stream>>>(wk, kvT, DD, DD);
  transpose_bf16<<<dim3(12, 12, 1), 256, 0, stream>>>(wv, kvT + (size_t)DD * DD, DD, DD);
  transpose_bf16<<<dim3(12, 12, 1), 256, 0, stream>>>(wo, woT, DD, DD);
  transpose_bf16<<<dim3(12, 48, 8), 256, 0, stream>>>(w1, w1T, DD, HID);
  transpose_bf16<<<dim3(48, 12, 8), 256, 0, stream>>>(w2, w2T, HID, DD);

  convert_bf16<<<TD / 1024, 256, 0, stream>>>(x, xbf);
  ln_kernel_bf<<<TT, 256, 0, stream>>>(x, ln1_w, ln1_b, ln1bf);

  mgemm<0, 1><<<64 * 6, 256, 0, stream>>>(ln1bf, wqT, bq, nullptr, nullptr, qbf, DD, DD);
  mgemm<2, 1><<<64 * 12, 256, 0, stream>>>(xbf, kvT, bk, bv, nullptr, kvbf, KVSTR, DD);

  attn_mfma<<<dim3(SS / 64, BB, HH), 256, 0, stream>>>(qbf, kvbf, kvbf + DD, attbf);

  mgemm<1, 0><<<64 * 6, 256, 0, stream>>>(attbf, woT, bo, nullptr, x, x1, DD, DD);

  ln_kernel<<<TT, 256, 0, stream>>>(x1, ln2_w, ln2_b, tln);

  route_kernel<<<TT / 4, 256, 0, stream>>>(tln, wg, bg, idx, gate, cnt);
  prefix_kernel<<<1, 64, 0, stream>>>(cnt, off, tb, cur);
  scatter_kernel<<<TT / 256, 256, 0, stream>>>(idx, off, cur, perm);
  gather_bf16<<<TT / 8, 256, 0, stream>>>(tln, perm, Abf);

  egemm1<<<8 * 9 * 24, 256, 0, stream>>>(Abf, w1T, b1, off, tb, cnt, hbuf);
  egemm2<<<8 * 9 * 6, 256, 0, stream>>>(hbuf, w2T, b2, perm, off, tb, cnt, gate, x1, out);
}

// Round 6
// 753.089 us; speedup vs baseline: 4.5513x; 1.0281x over previous
//
#include <hip/hip_runtime.h>
#include <math.h>

#define SS 512
#define BB 16
#define DD 768
#define HH 12
#define HDIM 64
#define EE 8
#define HID 3072
#define TT 8192   // SS*BB tokens
#define EPSV 1e-5f
#define KVSTR 1536
#define ASTR 72   // attention LDS row stride in shorts (144 B, 16B-aligned)

typedef __attribute__((ext_vector_type(8))) short s16x8;
typedef __attribute__((ext_vector_type(4))) short s16x4;
typedef __attribute__((ext_vector_type(4))) float f32x4;

__device__ inline short f2bf(float f) {
  unsigned u = __builtin_bit_cast(unsigned, f);
  unsigned r = (u + 0x7fffu + ((u >> 16) & 1u)) >> 16;
  return (short)r;
}

// tanh-form GELU (max abs err ~3e-4, invisible under bf16 pipeline noise)
__device__ inline float gelu_f(float x) {
  float y = 0.7978845608028654f * (x + 0.044715f * x * x * x);
  float e = __expf(2.f * y);
  float t = 1.f - 2.f / (e + 1.f);
  return 0.5f * x * (1.f + t);
}

// async global->LDS DMA, 16B per lane; LDS dest = wave-uniform base + lane*16
__device__ inline void gl2lds16(const void* g, void* l) {
  __builtin_amdgcn_global_load_lds(
      (const __attribute__((address_space(1))) unsigned int*)g,
      (__attribute__((address_space(3))) unsigned int*)l, 16, 0, 0);
}

// ---------------- fp32 -> bf16 bulk convert ----------------
__global__ __launch_bounds__(256) void convert_bf16(const float* __restrict__ src,
    short* __restrict__ dst) {
  size_t g = (size_t)blockIdx.x * 256 + threadIdx.x;
  const float4 v = *(const float4*)(src + g * 4);
  s16x4 s; s.x = f2bf(v.x); s.y = f2bf(v.y); s.z = f2bf(v.z); s.w = f2bf(v.w);
  *(s16x4*)(dst + g * 4) = s;
}

// ---------------- transpose + convert: W[K,N] fp32 -> Wt[N,K] bf16 ----------------
__global__ __launch_bounds__(256) void transpose_bf16(const float* __restrict__ W,
    short* __restrict__ Wt, int K, int N) {
  const float* Wz = W + (size_t)blockIdx.z * K * N;
  short* Wtz = Wt + (size_t)blockIdx.z * K * N;
  int k0 = blockIdx.x * 64, n0 = blockIdx.y * 64;
  __shared__ float t[64][65];
  for (int i = threadIdx.x; i < 4096; i += 256) {
    int r = i >> 6, c = i & 63;
    t[r][c] = Wz[(size_t)(k0 + r) * N + n0 + c];
  }
  __syncthreads();
  for (int i = threadIdx.x; i < 4096; i += 256) {
    int r = i >> 6, c = i & 63;
    Wtz[(size_t)(n0 + r) * K + k0 + c] = f2bf(t[c][r]);
  }
}

// ---------------- LayerNorm (bf16 out) ----------------
__global__ __launch_bounds__(256) void ln_kernel_bf(const float* __restrict__ x,
    const float* __restrict__ w, const float* __restrict__ b, short* __restrict__ out) {
  int t = blockIdx.x, tid = threadIdx.x;
  const float* row = x + (size_t)t * DD;
  float s = 0.f, ss = 0.f;
  for (int i = tid; i < DD; i += 256) { float v = row[i]; s += v; ss += v * v; }
  for (int o = 32; o > 0; o >>= 1) { s += __shfl_down(s, o); ss += __shfl_down(ss, o); }
  __shared__ float sw[4], ssw[4];
  int wid = tid >> 6, lane = tid & 63;
  if (lane == 0) { sw[wid] = s; ssw[wid] = ss; }
  __syncthreads();
  if (tid == 0) {
    float s1 = sw[0] + sw[1] + sw[2] + sw[3];
    float s2 = ssw[0] + ssw[1] + ssw[2] + ssw[3];
    float mean = s1 / DD;
    float var = s2 / DD - mean * mean;
    sw[0] = mean; ssw[0] = rsqrtf(var + EPSV);
  }
  __syncthreads();
  float mean = sw[0], inv = ssw[0];
  short* orow = out + (size_t)t * DD;
  for (int i = tid; i < DD; i += 256) orow[i] = f2bf((row[i] - mean) * inv * w[i] + b[i]);
}

// ---------------- LayerNorm (fp32 out) ----------------
__global__ __launch_bounds__(256) void ln_kernel(const float* __restrict__ x,
    const float* __restrict__ w, const float* __restrict__ b, float* __restrict__ out) {
  int t = blockIdx.x, tid = threadIdx.x;
  const float* row = x + (size_t)t * DD;
  float s = 0.f, ss = 0.f;
  for (int i = tid; i < DD; i += 256) { float v = row[i]; s += v; ss += v * v; }
  for (int o = 32; o > 0; o >>= 1) { s += __shfl_down(s, o); ss += __shfl_down(ss, o); }
  __shared__ float sw[4], ssw[4];
  int wid = tid >> 6, lane = tid & 63;
  if (lane == 0) { sw[wid] = s; ssw[wid] = ss; }
  __syncthreads();
  if (tid == 0) {
    float s1 = sw[0] + sw[1] + sw[2] + sw[3];
    float s2 = ssw[0] + ssw[1] + ssw[2] + ssw[3];
    float mean = s1 / DD;
    float var = s2 / DD - mean * mean;
    sw[0] = mean; ssw[0] = rsqrtf(var + EPSV);
  }
  __syncthreads();
  float mean = sw[0], inv = ssw[0];
  float* orow = out + (size_t)t * DD;
  for (int i = tid; i < DD; i += 256) orow[i] = (row[i] - mean) * inv * w[i] + b[i];
}

// ---------------- bf16 MFMA GEMM, DMA staging + XOR-swizzled LDS ----------------
// LDS row r stores k-quarter q at position q ^ ((r>>1)&3)  -> 2-way (free) b128 reads.
// MODE 0: bias. MODE 1: bias + res(fp32). MODE 2: dual bias split at DD.
template<int MODE, int OUTBF>
__global__ __launch_bounds__(256) void mgemm(const short* __restrict__ A,
    const short* __restrict__ Wt, const float* __restrict__ bias,
    const float* __restrict__ bias2, const float* __restrict__ res,
    void* __restrict__ C, int N, int K) {
  const int bx = blockIdx.x;
  const int lid = bx >> 3;
  const int colt = lid >> 3, rband = lid & 7;
  const int bm = (((bx & 7) << 3) + rband) * 128;
  const int bn = colt * 128;
  __shared__ short As[128 * 32];
  __shared__ short Bs[128 * 32];
  const int tid = threadIdx.x;
  const int wave = tid >> 6, lane = tid & 63;
  const int wr = (wave >> 1) * 64, wc = (wave & 1) * 64;
  const int l16 = lane & 15, quad = lane >> 4;
  const int kq = (((lane & 3) ^ ((lane >> 3) & 3)) << 3);
  const int sw = ((l16 >> 1) & 3);
  const short* Ab = A + (size_t)(bm + (wave << 5) + (lane >> 2)) * K + kq;
  const short* Bb = Wt + (size_t)(bn + (wave << 5) + (lane >> 2)) * K + kq;
  short* lA = &As[(wave << 5) * 32];
  short* lB = &Bs[(wave << 5) * 32];
  f32x4 acc[4][4] = {};
  for (int k0 = 0; k0 < K; k0 += 32) {
    gl2lds16(Ab + k0, lA);
    gl2lds16(Ab + (size_t)16 * K + k0, lA + 512);
    gl2lds16(Bb + k0, lB);
    gl2lds16(Bb + (size_t)16 * K + k0, lB + 512);
    __syncthreads();
    s16x8 af[4], bfr[4];
#pragma unroll
    for (int i = 0; i < 4; ++i)
      af[i] = *(s16x8*)(&As[(wr + i * 16 + l16) * 32 + ((quad ^ sw) << 3)]);
#pragma unroll
    for (int j = 0; j < 4; ++j)
      bfr[j] = *(s16x8*)(&Bs[(wc + j * 16 + l16) * 32 + ((quad ^ sw) << 3)]);
#pragma unroll
    for (int i = 0; i < 4; ++i)
#pragma unroll
      for (int j = 0; j < 4; ++j)
        acc[i][j] = __builtin_amdgcn_mfma_f32_16x16x32_bf16(af[i], bfr[j], acc[i][j], 0, 0, 0);
    __syncthreads();
  }
#pragma unroll
  for (int i = 0; i < 4; ++i) {
#pragma unroll
    for (int r = 0; r < 4; ++r) {
      int row = bm + wr + i * 16 + quad * 4 + r;
#pragma unroll
      for (int j = 0; j < 4; ++j) {
        int col = bn + wc + j * 16 + l16;
        float bv = (MODE == 2) ? (col >= DD ? bias2[col - DD] : bias[col]) : bias[col];
        float val = acc[i][j][r] + bv;
        if (MODE == 1) val += res[(size_t)row * N + col];
        if (OUTBF) ((short*)C)[(size_t)row * N + col] = f2bf(val);
        else       ((float*)C)[(size_t)row * N + col] = val;
      }
    }
  }
}

// ---------------- flash attention, bf16 MFMA, bf16 IO ----------------
__global__ __launch_bounds__(256) void attn_mfma(const short* __restrict__ q,
    const short* __restrict__ k, const short* __restrict__ v, short* __restrict__ o) {
  const int qt = blockIdx.x, bidx = blockIdx.y, hidx = blockIdx.z;
  const int tid = threadIdx.x;
  const int wave = tid >> 6, lane = tid & 63;
  const int l16 = lane & 15, quad = lane >> 4;
  const int s0 = qt * 64;
  __shared__ short Qs[64 * ASTR];
  __shared__ short Ks[64 * ASTR];
  __shared__ short Vs[64 * ASTR];   // transposed: Vs[d][key]
  __shared__ short Ps[64 * ASTR];
  for (int i = tid; i < 512; i += 256) {
    int r = i >> 3, c8 = i & 7;
    *(s16x8*)(&Qs[r * ASTR + c8 * 8]) =
        *(const s16x8*)(q + ((size_t)(s0 + r) * BB + bidx) * DD + hidx * HDIM + c8 * 8);
  }
  __syncthreads();
  s16x8 af0 = *(s16x8*)(&Qs[(wave * 16 + l16) * ASTR + quad * 8]);
  s16x8 af1 = *(s16x8*)(&Qs[(wave * 16 + l16) * ASTR + 32 + quad * 8]);
  f32x4 oacc[4] = {};
  float mr[4], lr[4];
#pragma unroll
  for (int r = 0; r < 4; ++r) { mr[r] = -1e30f; lr[r] = 0.f; }

  for (int t0 = 0; t0 < SS; t0 += 64) {
    __syncthreads();
    for (int i = tid; i < 512; i += 256) {
      int r = i >> 3, c8 = i & 7;
      *(s16x8*)(&Ks[r * ASTR + c8 * 8]) =
          *(const s16x8*)(k + ((size_t)(t0 + r) * BB + bidx) * KVSTR + hidx * HDIM + c8 * 8);
    }
    for (int i = tid; i < 1024; i += 256) {
      int r = i >> 4, c4 = i & 15;
      s16x4 vv = *(const s16x4*)(v + ((size_t)(t0 + r) * BB + bidx) * KVSTR + hidx * HDIM + c4 * 4);
      Vs[(c4 * 4 + 0) * ASTR + r] = vv.x;
      Vs[(c4 * 4 + 1) * ASTR + r] = vv.y;
      Vs[(c4 * 4 + 2) * ASTR + r] = vv.z;
      Vs[(c4 * 4 + 3) * ASTR + r] = vv.w;
    }
    __syncthreads();
    f32x4 sc[4];
    const f32x4 zero = {};
#pragma unroll
    for (int j = 0; j < 4; ++j) {
      s16x8 kf0 = *(s16x8*)(&Ks[(j * 16 + l16) * ASTR + quad * 8]);
      s16x8 kf1 = *(s16x8*)(&Ks[(j * 16 + l16) * ASTR + 32 + quad * 8]);
      sc[j] = __builtin_amdgcn_mfma_f32_16x16x32_bf16(af0, kf0, zero, 0, 0, 0);
      sc[j] = __builtin_amdgcn_mfma_f32_16x16x32_bf16(af1, kf1, sc[j], 0, 0, 0);
#pragma unroll
      for (int r = 0; r < 4; ++r) sc[j][r] *= 0.125f;
    }
    float tm[4], alpha[4], rs[4];
#pragma unroll
    for (int r = 0; r < 4; ++r) {
      tm[r] = mr[r];
#pragma unroll
      for (int j = 0; j < 4; ++j) tm[r] = fmaxf(tm[r], sc[j][r]);
    }
#pragma unroll
    for (int mask = 1; mask < 16; mask <<= 1)
#pragma unroll
      for (int r = 0; r < 4; ++r) tm[r] = fmaxf(tm[r], __shfl_xor(tm[r], mask));
#pragma unroll
    for (int r = 0; r < 4; ++r) { alpha[r] = __expf(mr[r] - tm[r]); mr[r] = tm[r]; rs[r] = 0.f; }
#pragma unroll
    for (int j = 0; j < 4; ++j)
#pragma unroll
      for (int r = 0; r < 4; ++r) {
        float p = __expf(sc[j][r] - tm[r]);
        sc[j][r] = p; rs[r] += p;
      }
#pragma unroll
    for (int mask = 1; mask < 16; mask <<= 1)
#pragma unroll
      for (int r = 0; r < 4; ++r) rs[r] += __shfl_xor(rs[r], mask);
#pragma unroll
    for (int r = 0; r < 4; ++r) lr[r] = lr[r] * alpha[r] + rs[r];
#pragma unroll
    for (int j = 0; j < 4; ++j)
#pragma unroll
      for (int r = 0; r < 4; ++r)
        Ps[(wave * 16 + quad * 4 + r) * ASTR + j * 16 + l16] = f2bf(sc[j][r]);
#pragma unroll
    for (int jd = 0; jd < 4; ++jd)
#pragma unroll
      for (int r = 0; r < 4; ++r) oacc[jd][r] *= alpha[r];
    __syncthreads();
    s16x8 pf0 = *(s16x8*)(&Ps[(wave * 16 + l16) * ASTR + quad * 8]);
    s16x8 pf1 = *(s16x8*)(&Ps[(wave * 16 + l16) * ASTR + 32 + quad * 8]);
#pragma unroll
    for (int jd = 0; jd < 4; ++jd) {
      s16x8 vf0 = *(s16x8*)(&Vs[(jd * 16 + l16) * ASTR + quad * 8]);
      s16x8 vf1 = *(s16x8*)(&Vs[(jd * 16 + l16) * ASTR + 32 + quad * 8]);
      oacc[jd] = __builtin_amdgcn_mfma_f32_16x16x32_bf16(pf0, vf0, oacc[jd], 0, 0, 0);
      oacc[jd] = __builtin_amdgcn_mfma_f32_16x16x32_bf16(pf1, vf1, oacc[jd], 0, 0, 0);
    }
  }
#pragma unroll
  for (int r = 0; r < 4; ++r) {
    int row = s0 + wave * 16 + quad * 4 + r;
    float invl = 1.f / lr[r];
#pragma unroll
    for (int jd = 0; jd < 4; ++jd) {
      int d = jd * 16 + l16;
      o[((size_t)row * BB + bidx) * DD + hidx * HDIM + d] = f2bf(oacc[jd][r] * invl);
    }
  }
}

// ---------------- MoE routing ----------------
__global__ __launch_bounds__(256) void route_kernel(const float* __restrict__ tln,
    const float* __restrict__ wg, const float* __restrict__ bg,
    int* __restrict__ idx, float* __restrict__ gate, int* __restrict__ cnt) {
  int token = blockIdx.x * 4 + (threadIdx.x >> 6);
  int lane = threadIdx.x & 63;
  const float* row = tln + (size_t)token * DD;
  float acc[EE];
#pragma unroll
  for (int e = 0; e < EE; ++e) acc[e] = 0.f;
  for (int d = lane; d < DD; d += 64) {
    float tv = row[d];
#pragma unroll
    for (int e = 0; e < EE; ++e) acc[e] += tv * wg[d * EE + e];
  }
  for (int o = 32; o > 0; o >>= 1)
#pragma unroll
    for (int e = 0; e < EE; ++e) acc[e] += __shfl_down(acc[e], o);
  if (lane == 0) {
#pragma unroll
    for (int e = 0; e < EE; ++e) acc[e] += bg[e];
    int best = 0; float bm = acc[0];
#pragma unroll
    for (int e = 1; e < EE; ++e) if (acc[e] > bm) { bm = acc[e]; best = e; }
    float sum = 0.f;
#pragma unroll
    for (int e = 0; e < EE; ++e) sum += __expf(acc[e] - bm);
    idx[token] = best;
    gate[token] = 1.0f / sum;
    atomicAdd(&cnt[best], 1);
  }
}

__global__ void prefix_kernel(const int* __restrict__ cnt, int* __restrict__ off,
                              int* __restrict__ tb, int* __restrict__ cur) {
  if (threadIdx.x == 0 && blockIdx.x == 0) {
    int o = 0, t = 0;
    for (int e = 0; e < EE; ++e) {
      off[e] = o; tb[e] = t;
      o += cnt[e]; t += (cnt[e] + 127) >> 7;
      cur[e] = 0;
    }
    off[EE] = o; tb[EE] = t;
  }
}

__global__ __launch_bounds__(256) void scatter_kernel(const int* __restrict__ idx,
    const int* __restrict__ off, int* __restrict__ cur, int* __restrict__ perm) {
  int t = blockIdx.x * 256 + threadIdx.x;
  if (t < TT) {
    int e = idx[t];
    int p = atomicAdd(&cur[e], 1);
    perm[off[e] + p] = t;
  }
}

// ---------------- gather fp32 tln rows -> permuted bf16 A ----------------
__global__ __launch_bounds__(256) void gather_bf16(const float* __restrict__ tln,
    const int* __restrict__ perm, short* __restrict__ Abf) {
  int slot = blockIdx.x * 8 + (threadIdx.x >> 5);
  int l32 = threadIdx.x & 31;
  int tok = perm[slot];
  const float* src = tln + (size_t)tok * DD;
  short* dst = Abf + (size_t)slot * DD;
#pragma unroll
  for (int kk = 0; kk < 6; ++kk) {
    int base = kk * 128 + l32 * 4;
    const float4 vv = *(const float4*)(src + base);
    s16x4 s; s.x = f2bf(vv.x); s.y = f2bf(vv.y); s.z = f2bf(vv.z); s.w = f2bf(vv.w);
    *(s16x4*)(dst + base) = s;
  }
}

// ---------------- expert GEMM 1: h = gelu(Abf @ w1[e]) -> bf16 ----------------
__global__ __launch_bounds__(256) void egemm1(const short* __restrict__ Abf,
    const short* __restrict__ w1t, const float* __restrict__ b1,
    const int* __restrict__ off, const int* __restrict__ tb, const int* __restrict__ cnt,
    short* __restrict__ hbuf) {
  const int bx = blockIdx.x;
  const int lid = bx >> 3;
  const int rband = lid % 9, colt = lid / 9;
  const int row = (bx & 7) * 9 + rband;
  if (row >= tb[EE]) return;
  int e = 0;
  while (e < EE - 1 && tb[e + 1] <= row) ++e;
  const int lt = row - tb[e];
  const int cnte = cnt[e];
  const int slot0 = off[e] + lt * 128;
  const int bn = colt * 128;
  const int tid = threadIdx.x;
  const int wave = tid >> 6, lane = tid & 63;
  const int wr = (wave >> 1) * 64, wc = (wave & 1) * 64;
  const int l16 = lane & 15, quad = lane >> 4;
  const int kq = (((lane & 3) ^ ((lane >> 3) & 3)) << 3);
  const int sw = ((l16 >> 1) & 3);
  __shared__ short As[128 * 32];
  __shared__ short Bs[128 * 32];
  f32x4 acc[4][4] = {};
  const short* Ab = Abf + (size_t)(slot0 + (wave << 5) + (lane >> 2)) * DD + kq;
  const short* Bb = w1t + (size_t)e * DD * HID
                  + (size_t)(bn + (wave << 5) + (lane >> 2)) * DD + kq;
  short* lA = &As[(wave << 5) * 32];
  short* lB = &Bs[(wave << 5) * 32];
  for (int k0 = 0; k0 < DD; k0 += 32) {
    gl2lds16(Ab + k0, lA);
    gl2lds16(Ab + (size_t)16 * DD + k0, lA + 512);
    gl2lds16(Bb + k0, lB);
    gl2lds16(Bb + (size_t)16 * DD + k0, lB + 512);
    __syncthreads();
    s16x8 af[4], bfr[4];
#pragma unroll
    for (int i = 0; i < 4; ++i)
      af[i] = *(s16x8*)(&As[(wr + i * 16 + l16) * 32 + ((quad ^ sw) << 3)]);
#pragma unroll
    for (int j = 0; j < 4; ++j)
      bfr[j] = *(s16x8*)(&Bs[(wc + j * 16 + l16) * 32 + ((quad ^ sw) << 3)]);
#pragma unroll
    for (int i = 0; i < 4; ++i)
#pragma unroll
      for (int j = 0; j < 4; ++j)
        acc[i][j] = __builtin_amdgcn_mfma_f32_16x16x32_bf16(af[i], bfr[j], acc[i][j], 0, 0, 0);
    __syncthreads();
  }
#pragma unroll
  for (int i = 0; i < 4; ++i) {
#pragma unroll
    for (int r = 0; r < 4; ++r) {
      int rl = wr + i * 16 + quad * 4 + r;
      if (lt * 128 + rl >= cnte) continue;
#pragma unroll
      for (int j = 0; j < 4; ++j) {
        int col = bn + wc + j * 16 + l16;
        float xv = acc[i][j][r] + b1[e * HID + col];
        hbuf[(size_t)(slot0 + rl) * HID + col] = f2bf(gelu_f(xv));
      }
    }
  }
}

// ---------------- expert GEMM 2: out = x1 + gate*(h @ w2[e] + b2) ----------------
__global__ __launch_bounds__(256) void egemm2(const short* __restrict__ hbuf,
    const short* __restrict__ w2t, const float* __restrict__ b2,
    const int* __restrict__ perm, const int* __restrict__ off,
    const int* __restrict__ tb, const int* __restrict__ cnt,
    const float* __restrict__ gate, const float* __restrict__ x1,
    float* __restrict__ out) {
  const int bx = blockIdx.x;
  const int lid = bx >> 3;
  const int colt = lid % 6, rband = lid / 6;
  const int row = (bx & 7) * 9 + rband;
  if (row >= tb[EE]) return;
  int e = 0;
  while (e < EE - 1 && tb[e + 1] <= row) ++e;
  const int lt = row - tb[e];
  const int cnte = cnt[e];
  const int slot0 = off[e] + lt * 128;
  const int bn = colt * 128;
  const int tid = threadIdx.x;
  const int wave = tid >> 6, lane = tid & 63;
  const int wr = (wave >> 1) * 64, wc = (wave & 1) * 64;
  const int l16 = lane & 15, quad = lane >> 4;
  const int kq = (((lane & 3) ^ ((lane >> 3) & 3)) << 3);
  const int sw = ((l16 >> 1) & 3);
  __shared__ short As[128 * 32];
  __shared__ short Bs[128 * 32];
  __shared__ int stok[128];
  if (tid < 128) stok[tid] = (lt * 128 + tid < cnte) ? perm[slot0 + tid] : -1;
  f32x4 acc[4][4] = {};
  const short* Ab = hbuf + (size_t)(slot0 + (wave << 5) + (lane >> 2)) * HID + kq;
  const short* Bb = w2t + (size_t)e * HID * DD
                  + (size_t)(bn + (wave << 5) + (lane >> 2)) * HID + kq;
  short* lA = &As[(wave << 5) * 32];
  short* lB = &Bs[(wave << 5) * 32];
  for (int k0 = 0; k0 < HID; k0 += 32) {
    gl2lds16(Ab + k0, lA);
    gl2lds16(Ab + (size_t)16 * HID + k0, lA + 512);
    gl2lds16(Bb + k0, lB);
    gl2lds16(Bb + (size_t)16 * HID + k0, lB + 512);
    __syncthreads();
    s16x8 af[4], bfr[4];
#pragma unroll
    for (int i = 0; i < 4; ++i)
      af[i] = *(s16x8*)(&As[(wr + i * 16 + l16) * 32 + ((quad ^ sw) << 3)]);
#pragma unroll
    for (int j = 0; j < 4; ++j)
      bfr[j] = *(s16x8*)(&Bs[(wc + j * 16 + l16) * 32 + ((quad ^ sw) << 3)]);
#pragma unroll
    for (int i = 0; i < 4; ++i)
#pragma unroll
      for (int j = 0; j < 4; ++j)
        acc[i][j] = __builtin_amdgcn_mfma_f32_16x16x32_bf16(af[i], bfr[j], acc[i][j], 0, 0, 0);
    __syncthreads();
  }
#pragma unroll
  for (int i = 0; i < 4; ++i) {
#pragma unroll
    for (int r = 0; r < 4; ++r) {
      int rl = wr + i * 16 + quad * 4 + r;
      if (lt * 128 + rl >= cnte) continue;
      int tok = stok[rl];
      float g = gate[tok];
#pragma unroll
      for (int j = 0; j < 4; ++j) {
        int col = bn + wc + j * 16 + l16;
        float val = acc[i][j][r] + b2[e * DD + col];
        out[(size_t)tok * DD + col] = x1[(size_t)tok * DD + col] + g * val;
      }
    }
  }
}

extern "C" void kernel_launch(void* const* d_in, const int* in_sizes, int n_in,
                              void* d_out, int out_size, void* d_ws, size_t ws_size,
                              hipStream_t stream) {
  const float* x     = (const float*)d_in[0];
  const float* ln1_w = (const float*)d_in[1];
  const float* ln1_b = (const float*)d_in[2];
  const float* wq    = (const float*)d_in[3];
  const float* bq    = (const float*)d_in[4];
  const float* wk    = (const float*)d_in[5];
  const float* bk    = (const float*)d_in[6];
  const float* wv    = (const float*)d_in[7];
  const float* bv    = (const float*)d_in[8];
  const float* wo    = (const float*)d_in[9];
  const float* bo    = (const float*)d_in[10];
  const float* ln2_w = (const float*)d_in[11];
  const float* ln2_b = (const float*)d_in[12];
  const float* wg    = (const float*)d_in[13];
  const float* bg    = (const float*)d_in[14];
  const float* w1    = (const float*)d_in[15];
  const float* b1    = (const float*)d_in[16];
  const float* w2    = (const float*)d_in[17];
  const float* b2    = (const float*)d_in[18];
  float* out = (float*)d_out;
  float* ws = (float*)d_ws;

  const size_t TD = (size_t)TT * DD;
  float* x1   = ws;                 // [TT,DD] fp32 (attn residual out)
  float* tln  = ws + TD;            // [TT,DD] fp32 (ln2 out, route input)
  short* sbase = (short*)(ws + 2 * TD);
  short* xbf   = sbase;                         // [TT,DD]; later reused as Abf
  short* Abf   = sbase;                         // alias (gather after xbf dead)
  short* ln1bf = sbase + TD + 128 * DD;         // [TT,DD]; later reused as attbf
  short* attbf = ln1bf;                         // alias (ln1bf dead after Q-proj)
  short* qbf   = ln1bf + TD;                    // [TT,DD]
  short* kvbf  = qbf + TD;                      // [TT,KVSTR]
  short* hbuf  = kvbf + (size_t)TT * KVSTR;     // [(TT+128),HID]
  short* wqT   = hbuf + (size_t)(TT + 128) * HID;
  short* kvT   = wqT + (size_t)DD * DD;
  short* woT   = kvT + (size_t)KVSTR * DD;
  short* w1T   = woT + (size_t)DD * DD;
  short* w2T   = w1T + (size_t)EE * DD * HID;
  int*   meta  = (int*)(w2T + (size_t)EE * HID * DD);
  int*   idx   = meta;
  float* gate  = (float*)(meta + TT);
  int*   perm  = meta + 2 * TT;
  int*   cnt   = meta + 3 * TT;
  int*   off   = cnt + 8;
  int*   tb    = off + 9;
  int*   cur   = tb + 9;

  hipMemsetAsync(cnt, 0, 8 * sizeof(int), stream);

  // weight transposes (fp32 -> bf16 [N,K])
  transpose_bf16<<<dim3(12, 12, 1), 256, 0, stream>>>(wq, wqT, DD, DD);
  transpose_bf16<<<dim3(12, 12, 1), 256, 0, stream>>>(wk, kvT, DD, DD);
  transpose_bf16<<<dim3(12, 12, 1), 256, 0, stream>>>(wv, kvT + (size_t)DD * DD, DD, DD);
  transpose_bf16<<<dim3(12, 12, 1), 256, 0, stream>>>(wo, woT, DD, DD);
  transpose_bf16<<<dim3(12, 48, 8), 256, 0, stream>>>(w1, w1T, DD, HID);
  transpose_bf16<<<dim3(48, 12, 8), 256, 0, stream>>>(w2, w2T, HID, DD);

  convert_bf16<<<TD / 1024, 256, 0, stream>>>(x, xbf);
  ln_kernel_bf<<<TT, 256, 0, stream>>>(x, ln1_w, ln1_b, ln1bf);

  mgemm<0, 1><<<64 * 6, 256, 0, stream>>>(ln1bf, wqT, bq, nullptr, nullptr, qbf, DD, DD);
  mgemm<2, 1><<<64 * 12, 256, 0, stream>>>(xbf, kvT, bk, bv, nullptr, kvbf, KVSTR, DD);

  attn_mfma<<<dim3(SS / 64, BB, HH), 256, 0, stream>>>(qbf, kvbf, kvbf + DD, attbf);

  mgemm<1, 0><<<64 * 6, 256, 0, stream>>>(attbf, woT, bo, nullptr, x, x1, DD, DD);

  ln_kernel<<<TT, 256, 0, stream>>>(x1, ln2_w, ln2_b, tln);

  route_kernel<<<TT / 4, 256, 0, stream>>>(tln, wg, bg, idx, gate, cnt);
  prefix_kernel<<<1, 64, 0, stream>>>(cnt, off, tb, cur);
  scatter_kernel<<<TT / 256, 256, 0, stream>>>(idx, off, cur, perm);
  gather_bf16<<<TT / 8, 256, 0, stream>>>(tln, perm, Abf);

  egemm1<<<8 * 9 * 24, 256, 0, stream>>>(Abf, w1T, b1, off, tb, cnt, hbuf);
  egemm2<<<8 * 9 * 6, 256, 0, stream>>>(hbuf, w2T, b2, perm, off, tb, cnt, gate, x1, out);
}